// Round 1
// baseline (5521.067 us; speedup 1.0000x reference)
//
#include <hip/hip_runtime.h>
#include <cstdint>
#include <cstddef>

#define DEVI __device__ __forceinline__

typedef __attribute__((ext_vector_type(8))) short short8;
typedef __attribute__((ext_vector_type(4))) float f32x4;
using u16 = unsigned short;

constexpr int BSZ = 32, TSZ = 128, VSZ = 50257, HSZ = 1024;
constexpr int M4 = BSZ * TSZ;          // 4096 rows
constexpr int FH = 4 * HSZ;            // 4096 gate rows
constexpr long long OUT_LOGP = (long long)M4 * VSZ;  // 205,852,672

// ---------- small helpers ----------
DEVI u16 f2bf(float f) {
  unsigned u = __float_as_uint(f);
  unsigned r = (u + 0x7fffu + ((u >> 16) & 1u)) >> 16;
  return (u16)r;
}
DEVI float bf2f(u16 u) { return __uint_as_float(((unsigned)u) << 16); }
DEVI float sigm(float x) { return 1.f / (1.f + __expf(-x)); }
DEVI float tanh_fast(float x) { return 1.f - 2.f / (1.f + __expf(2.f * x)); }

DEVI f32x4 mfma16(short8 a, short8 b, f32x4 c) {
  return __builtin_amdgcn_mfma_f32_16x16x32_bf16(a, b, c, 0, 0, 0);
}

DEVI void gld16(const void* g, void* l) {
  auto gp = (const __attribute__((address_space(1))) unsigned int*)g;
  auto lp = (__attribute__((address_space(3))) unsigned int*)l;
  __builtin_amdgcn_global_load_lds(gp, lp, 16, 0, 0);
}

// ---------- prep: bias0 = b_ih0+b_hh0, zero rowsum + barrier words ----------
__global__ void prep_misc(const float* __restrict__ bih, const float* __restrict__ bhh,
                          float* __restrict__ bias0, float* __restrict__ rowsum,
                          unsigned* __restrict__ bar) {
  int i = blockIdx.x * 256 + threadIdx.x;
  if (i < FH) { bias0[i] = bih[i] + bhh[i]; rowsum[i] = 0.f; }
  if (i < 8) bar[i] = 0u;
}

// ---------- f32 -> bf16 convert ----------
__global__ void cvt_bf16(const float* __restrict__ src, u16* __restrict__ dst, int n4) {
  int i = blockIdx.x * blockDim.x + threadIdx.x;
  int stride = gridDim.x * blockDim.x;
  for (; i < n4; i += stride) {
    float4 v = ((const float4*)src)[i];
    ushort4 o; o.x = f2bf(v.x); o.y = f2bf(v.y); o.z = f2bf(v.z); o.w = f2bf(v.w);
    ((ushort4*)dst)[i] = o;
  }
}

// ---------- embedding gather -> Xbf [T,B,H] bf16 ----------
__global__ __launch_bounds__(256) void embed_kernel(const int* __restrict__ tok,
                                                    const float* __restrict__ emb,
                                                    u16* __restrict__ X) {
  int m = blockIdx.x;                // m = t*32 + b
  int t = m >> 5, b = m & 31;
  int token = tok[b * TSZ + t];
  const float4* src = (const float4*)(emb + (size_t)token * HSZ);
  int i = threadIdx.x;               // 256 threads x 4 elems
  float4 v = src[i];
  ushort4 o; o.x = f2bf(v.x); o.y = f2bf(v.y); o.z = f2bf(v.z); o.w = f2bf(v.w);
  *(ushort4*)(X + (size_t)m * HSZ + i * 4) = o;
}

// ---------- m97-style 128x128 bf16 MFMA GEMM: C = A * B^T (+bias) ----------
// EPI 0: C bf16 (gate pre-activations). EPI 1: C f32 + bias + per-row sum(exp) atomics.
// BCVT: B source is f32, converted in-kernel (reg-staged) instead of bf16 global_load_lds.
template <int EPI, bool BCVT>
__global__ __launch_bounds__(256) void gemm_bt(const u16* __restrict__ A,
                                               const void* __restrict__ Bsrc,
                                               void* __restrict__ Cout,
                                               const float* __restrict__ bias,
                                               float* __restrict__ rowsum,
                                               int nm, int nn, int N, int K, int ldc) {
  __shared__ u16 As[128 * 32];
  __shared__ u16 Bs[128 * 32];
  const int tid = threadIdx.x;
  int gsz = nm * nn;
  int id = blockIdx.x;
  int wg = ((gsz & 7) == 0) ? (id % 8) * (gsz >> 3) + (id >> 3) : id;  // XCD swizzle
  const int bm = wg % nm, bn = wg / nm;
  const int m0 = bm * 128, n0 = bn * 128;
  const int l = tid & 63, wid = tid >> 6;
  const int wm = wid >> 1, wn = wid & 1;

  const int srow = tid >> 2, sq = tid & 3;
  const int arow0 = m0 + srow, arow1 = m0 + 64 + srow;
  int brow0 = n0 + srow;      if (brow0 > N - 1) brow0 = N - 1;
  int brow1 = n0 + 64 + srow; if (brow1 > N - 1) brow1 = N - 1;

  const u16* Bbf = (const u16*)Bsrc;
  const float* Bf32 = (const float*)Bsrc;
  u16* AsW = As + (size_t)(tid >> 6) * 512;   // wave-uniform LDS staging base
  u16* BsW = Bs + (size_t)(tid >> 6) * 512;

  f32x4 acc[4][4];
  f32x4 z = {0.f, 0.f, 0.f, 0.f};
#pragma unroll
  for (int a = 0; a < 4; ++a)
#pragma unroll
    for (int b = 0; b < 4; ++b) acc[a][b] = z;

  for (int k0 = 0; k0 < K; k0 += 32) {
    gld16(A + (size_t)arow0 * K + k0 + sq * 8, AsW);
    gld16(A + (size_t)arow1 * K + k0 + sq * 8, AsW + 2048);
    if (!BCVT) {
      gld16(Bbf + (size_t)brow0 * K + k0 + sq * 8, BsW);
      gld16(Bbf + (size_t)brow1 * K + k0 + sq * 8, BsW + 2048);
    } else {
      const float* s0 = Bf32 + (size_t)brow0 * K + k0 + sq * 8;
      const float* s1 = Bf32 + (size_t)brow1 * K + k0 + sq * 8;
      float4 x0 = *(const float4*)s0, y0 = *(const float4*)(s0 + 4);
      float4 x1 = *(const float4*)s1, y1 = *(const float4*)(s1 + 4);
      short8 v0, v1;
      v0[0]=(short)f2bf(x0.x); v0[1]=(short)f2bf(x0.y); v0[2]=(short)f2bf(x0.z); v0[3]=(short)f2bf(x0.w);
      v0[4]=(short)f2bf(y0.x); v0[5]=(short)f2bf(y0.y); v0[6]=(short)f2bf(y0.z); v0[7]=(short)f2bf(y0.w);
      v1[0]=(short)f2bf(x1.x); v1[1]=(short)f2bf(x1.y); v1[2]=(short)f2bf(x1.z); v1[3]=(short)f2bf(x1.w);
      v1[4]=(short)f2bf(y1.x); v1[5]=(short)f2bf(y1.y); v1[6]=(short)f2bf(y1.z); v1[7]=(short)f2bf(y1.w);
      *(short8*)&Bs[(size_t)tid * 8] = v0;
      *(short8*)&Bs[(size_t)tid * 8 + 2048] = v1;
    }
    __syncthreads();
    short8 af[4], bfr[4];
#pragma unroll
    for (int x = 0; x < 4; ++x) {
      int ar = wm * 64 + x * 16 + (l & 15);
      af[x] = *(const short8*)&As[ar * 32 + ((l >> 4) << 3)];
      int br = wn * 64 + x * 16 + (l & 15);
      bfr[x] = *(const short8*)&Bs[br * 32 + ((l >> 4) << 3)];
    }
#pragma unroll
    for (int mf = 0; mf < 4; ++mf)
#pragma unroll
      for (int nf = 0; nf < 4; ++nf)
        acc[mf][nf] = mfma16(af[mf], bfr[nf], acc[mf][nf]);
    __syncthreads();
  }

  if constexpr (EPI == 0) {
    u16* C = (u16*)Cout;
#pragma unroll
    for (int nf = 0; nf < 4; ++nf) {
      int cg = n0 + wn * 64 + nf * 16 + (l & 15);
      float bv = bias[cg];
#pragma unroll
      for (int mf = 0; mf < 4; ++mf) {
        int r = m0 + wm * 64 + mf * 16 + ((l >> 4) << 2);
#pragma unroll
        for (int j = 0; j < 4; ++j)
          C[(size_t)(r + j) * ldc + cg] = f2bf(acc[mf][nf][j] + bv);
      }
    }
  } else {
    float* C = (float*)Cout;
    int cg[4]; float bv[4]; bool ok[4];
#pragma unroll
    for (int nf = 0; nf < 4; ++nf) {
      cg[nf] = n0 + wn * 64 + nf * 16 + (l & 15);
      ok[nf] = (cg[nf] < N);
      bv[nf] = ok[nf] ? bias[cg[nf]] : 0.f;
    }
#pragma unroll
    for (int mf = 0; mf < 4; ++mf) {
#pragma unroll
      for (int j = 0; j < 4; ++j) {
        int r = m0 + wm * 64 + mf * 16 + ((l >> 4) << 2) + j;
        float e = 0.f;
#pragma unroll
        for (int nf = 0; nf < 4; ++nf) {
          float v = acc[mf][nf][j] + bv[nf];
          if (ok[nf]) { C[(size_t)r * ldc + cg[nf]] = v; e += __expf(v); }
        }
        e += __shfl_xor(e, 1, 16); e += __shfl_xor(e, 2, 16);
        e += __shfl_xor(e, 4, 16); e += __shfl_xor(e, 8, 16);
        if ((l & 15) == 0) atomicAdd(&rowsum[r], e);
      }
    }
  }
}

// ---------- cooperative 2-layer pipelined LSTM recurrence ----------
struct LstmArgs {
  const u16* G0;       // [T*B, 4H] bf16 precomputed x@Wih0^T + b
  const float* Wih;    // [2,4H,H] f32
  const float* Whh;    // [2,4H,H] f32
  const float* bih, *bhh, *h0, *c0;
  u16* H0;             // [T+1, B, H] bf16 (slot s holds h0_{s-1})
  u16* H1;             // [B, T, H]  bf16
  u16* h1init;         // [B, H]
  float* out_hc;       // d_out + OUT_LOGP  (hT[2][B][H] then cT[2][B][H])
  unsigned* bar;
};

DEVI void gridbar(unsigned* bar, unsigned& gen, int l) {
  __syncthreads();
  ++gen;
  if (l == 0) {
    unsigned prev = __hip_atomic_fetch_add(&bar[0], 1u, __ATOMIC_ACQ_REL, __HIP_MEMORY_SCOPE_AGENT);
    if (prev == 255u) {
      __hip_atomic_store(&bar[0], 0u, __ATOMIC_RELAXED, __HIP_MEMORY_SCOPE_AGENT);
      __hip_atomic_store(&bar[1], gen, __ATOMIC_RELEASE, __HIP_MEMORY_SCOPE_AGENT);
    } else {
      while (__hip_atomic_load(&bar[1], __ATOMIC_RELAXED, __HIP_MEMORY_SCOPE_AGENT) < gen)
        __builtin_amdgcn_s_sleep(1);
      __builtin_amdgcn_fence(__ATOMIC_ACQUIRE, "agent");
    }
  }
  __syncthreads();
}

// stage 16 rows (4 units x 4 gates) of a [4H,H] f32 matrix into LDS bf16, XOR-swizzled
DEVI void stage16(const float* W, int j0, u16* lds, int l) {
  const int ri = l >> 2, q = l & 3;
  const int grow = ((ri >> 2) << 10) + j0 + (ri & 3);
  const float* src = W + (size_t)grow * HSZ + q * 256;
  char* row = (char*)lds + ri * 2048;
  const int sw = (ri & 7) << 4;
  for (int kk = 0; kk < 256; kk += 8) {
    float4 x = *(const float4*)(src + kk);
    float4 y = *(const float4*)(src + kk + 4);
    short8 v;
    v[0]=(short)f2bf(x.x); v[1]=(short)f2bf(x.y); v[2]=(short)f2bf(x.z); v[3]=(short)f2bf(x.w);
    v[4]=(short)f2bf(y.x); v[5]=(short)f2bf(y.y); v[6]=(short)f2bf(y.z); v[7]=(short)f2bf(y.w);
    const int kbyte = (q * 256 + kk) * 2;
    *(short8*)(row + (kbyte ^ sw)) = v;
  }
}

DEVI short8 ldsB(const u16* lds, int l, int ks) {
  const int ri = l & 15;
  const int kbyte = ks * 64 + ((l >> 4) << 4);
  return *(const short8*)((const char*)lds + ri * 2048 + (kbyte ^ ((ri & 7) << 4)));
}

DEVI void ew(const float* gates, int l, int j0, float* cst, u16* hbase, size_t rstride,
             bool last, float* outh, float* outc) {
  const int u = l & 3;
#pragma unroll
  for (int p = 0; p < 2; ++p) {
    const int b = (l >> 2) + p * 16;
    float gi = gates[u * 36 + b];
    float gf = gates[(4 + u) * 36 + b];
    float gg = gates[(8 + u) * 36 + b];
    float go = gates[(12 + u) * 36 + b];
    float i_ = sigm(gi), f_ = sigm(gf), g_ = tanh_fast(gg), o_ = sigm(go);
    float c_ = f_ * cst[p] + i_ * g_;
    cst[p] = c_;
    float h_ = o_ * tanh_fast(c_);
    hbase[(size_t)b * rstride + j0 + u] = f2bf(h_);
    if (last) {
      outh[(size_t)b * HSZ + j0 + u] = h_;
      outc[(size_t)b * HSZ + j0 + u] = c_;
    }
  }
}

__global__ __launch_bounds__(64) void lstm_coop(LstmArgs A) {
  extern __shared__ char smem[];
  u16* Whh0L = (u16*)smem;
  u16* Wih1L = (u16*)(smem + 32768);
  u16* Whh1L = (u16*)(smem + 65536);
  float* gates = (float*)(smem + 98304);   // [16][36] f32
  float* bias1 = (float*)(smem + 100608);  // [16]
  const int wg = blockIdx.x, l = threadIdx.x;
  const int j0 = wg << 2;

  stage16(A.Whh, j0, Whh0L, l);
  stage16(A.Wih + (size_t)FH * HSZ, j0, Wih1L, l);
  stage16(A.Whh + (size_t)FH * HSZ, j0, Whh1L, l);
  if (l < 16) {
    int grow = ((l >> 2) << 10) + j0 + (l & 3);
    bias1[l] = A.bih[FH + grow] + A.bhh[FH + grow];
  }
  {
    int gid = (wg << 6) + l;
#pragma unroll
    for (int e = gid * 2; e < gid * 2 + 2; ++e) {
      A.H0[e] = f2bf(A.h0[e]);                 // layer0 h init -> slot 0
      A.h1init[e] = f2bf(A.h0[BSZ * HSZ + e]); // layer1 h init
    }
  }
  float c0st[2], c1st[2];
  {
    int u = l & 3, b1 = l >> 2;
    c0st[0] = A.c0[(size_t)b1 * HSZ + j0 + u];
    c0st[1] = A.c0[(size_t)(b1 + 16) * HSZ + j0 + u];
    c1st[0] = A.c0[BSZ * HSZ + (size_t)b1 * HSZ + j0 + u];
    c1st[1] = A.c0[BSZ * HSZ + (size_t)(b1 + 16) * HSZ + j0 + u];
  }
  unsigned gen = 0;
  gridbar(A.bar, gen, l);

  const int ri = l & 15;
  const int grow = ((ri >> 2) << 10) + j0 + (ri & 3);

  for (int tau = 0; tau <= TSZ; ++tau) {
    if (tau < TSZ) {                       // ---- layer 0, t = tau ----
      const int t = tau;
      f32x4 acc0, acc1;
      const u16* g0p = A.G0 + (size_t)t * BSZ * FH + grow;
#pragma unroll
      for (int j = 0; j < 4; ++j) {
        int brow = ((l >> 4) << 2) + j;
        acc0[j] = bf2f(g0p[(size_t)brow * FH]);
        acc1[j] = bf2f(g0p[(size_t)(brow + 16) * FH]);
      }
      const u16* hprev = A.H0 + (size_t)t * BSZ * HSZ;
      for (int ks = 0; ks < 32; ++ks) {
        const int kb = ks * 32 + ((l >> 4) << 3);
        short8 a0 = *(const short8*)(hprev + (size_t)ri * HSZ + kb);
        short8 a1 = *(const short8*)(hprev + (size_t)(ri + 16) * HSZ + kb);
        short8 bf = ldsB(Whh0L, l, ks);
        acc0 = mfma16(a0, bf, acc0);
        acc1 = mfma16(a1, bf, acc1);
      }
      *(f32x4*)&gates[ri * 36 + ((l >> 4) << 2)] = acc0;
      *(f32x4*)&gates[ri * 36 + 16 + ((l >> 4) << 2)] = acc1;
      __syncthreads();
      ew(gates, l, j0, c0st, A.H0 + (size_t)(t + 1) * BSZ * HSZ, HSZ,
         t == TSZ - 1, A.out_hc, A.out_hc + 2 * BSZ * HSZ);
      __syncthreads();
    }
    if (tau >= 1) {                        // ---- layer 1, t = tau-1 ----
      const int t = tau - 1;
      float bv = bias1[ri];
      f32x4 acc0 = {bv, bv, bv, bv}, acc1 = {bv, bv, bv, bv};
      const u16* x1 = A.H0 + (size_t)(t + 1) * BSZ * HSZ;
      const u16* hp = (t == 0) ? A.h1init : A.H1 + (size_t)(t - 1) * HSZ;
      const size_t hstride = (t == 0) ? (size_t)HSZ : (size_t)TSZ * HSZ;
      for (int ks = 0; ks < 32; ++ks) {
        const int kb = ks * 32 + ((l >> 4) << 3);
        short8 a0 = *(const short8*)(x1 + (size_t)ri * HSZ + kb);
        short8 a1 = *(const short8*)(x1 + (size_t)(ri + 16) * HSZ + kb);
        short8 b0 = ldsB(Wih1L, l, ks);
        acc0 = mfma16(a0, b0, acc0);
        acc1 = mfma16(a1, b0, acc1);
        short8 h0f = *(const short8*)(hp + (size_t)ri * hstride + kb);
        short8 h1f = *(const short8*)(hp + (size_t)(ri + 16) * hstride + kb);
        short8 b1 = ldsB(Whh1L, l, ks);
        acc0 = mfma16(h0f, b1, acc0);
        acc1 = mfma16(h1f, b1, acc1);
      }
      __syncthreads();
      *(f32x4*)&gates[ri * 36 + ((l >> 4) << 2)] = acc0;
      *(f32x4*)&gates[ri * 36 + 16 + ((l >> 4) << 2)] = acc1;
      __syncthreads();
      ew(gates, l, j0, c1st, A.H1 + (size_t)t * HSZ, (size_t)TSZ * HSZ,
         t == TSZ - 1, A.out_hc + BSZ * HSZ, A.out_hc + 3 * BSZ * HSZ);
    }
    gridbar(A.bar, gen, l);
  }
}

// ---------- logsumexp finish ----------
__global__ void lse_kernel(float* __restrict__ rowsum, int n) {
  int i = blockIdx.x * 256 + threadIdx.x;
  if (i < n) rowsum[i] = logf(rowsum[i]);
}

__global__ __launch_bounds__(256) void lsm_finish(float* __restrict__ C,
                                                  const float* __restrict__ lse, int Vd) {
  int row = blockIdx.y;
  int col = blockIdx.x * 256 + threadIdx.x;
  if (col < Vd) {
    float s = lse[row];
    size_t idx = (size_t)row * Vd + col;
    C[idx] -= s;
  }
}

// ---------- launcher ----------
extern "C" void kernel_launch(void* const* d_in, const int* in_sizes, int n_in,
                              void* d_out, int out_size, void* d_ws, size_t ws_size,
                              hipStream_t stream) {
  const int* tokens = (const int*)d_in[0];
  const float* emb = (const float*)d_in[1];
  const float* Wih = (const float*)d_in[2];
  const float* Whh = (const float*)d_in[3];
  const float* bih = (const float*)d_in[4];
  const float* bhh = (const float*)d_in[5];
  const float* Wout = (const float*)d_in[6];
  const float* bout = (const float*)d_in[7];
  const float* h0 = (const float*)d_in[8];
  const float* c0 = (const float*)d_in[9];
  float* out = (float*)d_out;

  char* w = (char*)d_ws;
  size_t o = 0;
  u16* Xbf = (u16*)(w + o);    o += (size_t)M4 * HSZ * 2;
  u16* Wih0bf = (u16*)(w + o); o += (size_t)FH * HSZ * 2;
  u16* G0 = (u16*)(w + o);     o += (size_t)M4 * FH * 2;
  u16* H0 = (u16*)(w + o);     o += (size_t)(TSZ + 1) * BSZ * HSZ * 2;
  u16* H1 = (u16*)(w + o);     o += (size_t)BSZ * TSZ * HSZ * 2;
  u16* h1init = (u16*)(w + o); o += (size_t)BSZ * HSZ * 2;
  float* bias0 = (float*)(w + o);  o += FH * 4;
  float* rowsum = (float*)(w + o); o += M4 * 4;
  unsigned* bar = (unsigned*)(w + o); o += 256;
  u16* Woutbf = (u16*)(w + o);
  size_t need_full = o + (size_t)VSZ * HSZ * 2;
  const bool bcvt = (ws_size < need_full);   // fallback: read W_out f32 in-kernel

  prep_misc<<<16, 256, 0, stream>>>(bih, bhh, bias0, rowsum, bar);
  cvt_bf16<<<2048, 256, 0, stream>>>(Wih, Wih0bf, FH * HSZ / 4);
  if (!bcvt)
    cvt_bf16<<<4096, 256, 0, stream>>>(Wout, Woutbf, (int)((size_t)VSZ * HSZ / 4));
  embed_kernel<<<M4, 256, 0, stream>>>(tokens, emb, Xbf);
  gemm_bt<0, false><<<32 * 32, 256, 0, stream>>>(Xbf, Wih0bf, G0, bias0, nullptr,
                                                 32, 32, FH, HSZ, FH);

  LstmArgs la{G0, Wih, Whh, bih, bhh, h0, c0, H0, H1, h1init,
              out + (size_t)OUT_LOGP, bar};
  void* kargs[] = {&la};
  hipFuncSetAttribute((const void*)lstm_coop, hipFuncAttributeMaxDynamicSharedMemorySize, 100672);
  hipLaunchCooperativeKernel((const void*)lstm_coop, dim3(256), dim3(64), kargs, 100672, stream);

  const int nn = (VSZ + 127) / 128;  // 393
  if (!bcvt)
    gemm_bt<1, false><<<32 * nn, 256, 0, stream>>>(H1, Woutbf, out, bout, rowsum,
                                                   32, nn, VSZ, HSZ, VSZ);
  else
    gemm_bt<1, true><<<32 * nn, 256, 0, stream>>>(H1, Wout, out, bout, rowsum,
                                                  32, nn, VSZ, HSZ, VSZ);

  lse_kernel<<<16, 256, 0, stream>>>(rowsum, M4);
  lsm_finish<<<dim3((VSZ + 255) / 256, M4), 256, 0, stream>>>(out, rowsum, VSZ);
}

// Round 2
// 3825.750 us; speedup vs baseline: 1.4431x; 1.4431x over previous
//
#include <hip/hip_runtime.h>
#include <cstdint>
#include <cstddef>

#define DEVI __device__ __forceinline__

typedef __attribute__((ext_vector_type(8))) short short8;
typedef __attribute__((ext_vector_type(4))) float f32x4;
using u16 = unsigned short;

constexpr int BSZ = 32, TSZ = 128, VSZ = 50257, HSZ = 1024;
constexpr int M4 = BSZ * TSZ;          // 4096 rows
constexpr int FH = 4 * HSZ;            // 4096 gate rows
constexpr long long OUT_LOGP = (long long)M4 * VSZ;
constexpr int NBLK = 192;              // 64 layer0 + 128 layer1
constexpr unsigned GRPSZ = 24;         // 192 / 8 groups

// ---------- small helpers ----------
DEVI u16 f2bf(float f) {
  unsigned u = __float_as_uint(f);
  unsigned r = (u + 0x7fffu + ((u >> 16) & 1u)) >> 16;
  return (u16)r;
}
DEVI float bf2f(u16 u) { return __uint_as_float(((unsigned)u) << 16); }
DEVI float sigm(float x) { return 1.f / (1.f + __expf(-x)); }
DEVI float tanh_fast(float x) { return 1.f - 2.f / (1.f + __expf(2.f * x)); }

DEVI f32x4 mfma16(short8 a, short8 b, f32x4 c) {
  return __builtin_amdgcn_mfma_f32_16x16x32_bf16(a, b, c, 0, 0, 0);
}

DEVI void gld16(const void* g, void* l) {
  auto gp = (const __attribute__((address_space(1))) unsigned int*)g;
  auto lp = (__attribute__((address_space(3))) unsigned int*)l;
  __builtin_amdgcn_global_load_lds(gp, lp, 16, 0, 0);
}

// ---------- prep: bias0 = b_ih0+b_hh0, zero rowsum + barrier area ----------
__global__ void prep_misc(const float* __restrict__ bih, const float* __restrict__ bhh,
                          float* __restrict__ bias0, float* __restrict__ rowsum,
                          unsigned* __restrict__ bar) {
  int i = blockIdx.x * 256 + threadIdx.x;
  if (i < FH) { bias0[i] = bih[i] + bhh[i]; rowsum[i] = 0.f; }
  if (i < 1024) bar[i] = 0u;
}

// ---------- f32 -> bf16 convert ----------
__global__ void cvt_bf16(const float* __restrict__ src, u16* __restrict__ dst, int n4) {
  int i = blockIdx.x * blockDim.x + threadIdx.x;
  int stride = gridDim.x * blockDim.x;
  for (; i < n4; i += stride) {
    float4 v = ((const float4*)src)[i];
    ushort4 o; o.x = f2bf(v.x); o.y = f2bf(v.y); o.z = f2bf(v.z); o.w = f2bf(v.w);
    ((ushort4*)dst)[i] = o;
  }
}

// ---------- embedding gather -> Xbf [T*B, H] bf16 (m = t*32+b) ----------
__global__ __launch_bounds__(256) void embed_kernel(const int* __restrict__ tok,
                                                    const float* __restrict__ emb,
                                                    u16* __restrict__ X) {
  int m = blockIdx.x;
  int t = m >> 5, b = m & 31;
  int token = tok[b * TSZ + t];
  const float4* src = (const float4*)(emb + (size_t)token * HSZ);
  int i = threadIdx.x;
  float4 v = src[i];
  ushort4 o; o.x = f2bf(v.x); o.y = f2bf(v.y); o.z = f2bf(v.z); o.w = f2bf(v.w);
  *(ushort4*)(X + (size_t)m * HSZ + i * 4) = o;
}

// ---------- 128x128 bf16 MFMA GEMM: C = A * B^T ----------
// EPI 1: C f32 + bias[col] + per-row sum(exp) atomics (vocab projection).
// EPI 2: C bf16 + bias[row] (G0T = Wih0 @ X^T + b).
// BCVT: B source f32, converted in-register.
template <int EPI, bool BCVT>
__global__ __launch_bounds__(256) void gemm_bt(const u16* __restrict__ A,
                                               const void* __restrict__ Bsrc,
                                               void* __restrict__ Cout,
                                               const float* __restrict__ bias,
                                               float* __restrict__ rowsum,
                                               int nm, int nn, int N, int K, int ldc) {
  __shared__ u16 As[128 * 32];
  __shared__ u16 Bs[128 * 32];
  const int tid = threadIdx.x;
  int gsz = nm * nn;
  int id = blockIdx.x;
  int wg = ((gsz & 7) == 0) ? (id % 8) * (gsz >> 3) + (id >> 3) : id;
  const int bm = wg % nm, bn = wg / nm;
  const int m0 = bm * 128, n0 = bn * 128;
  const int l = tid & 63, wid = tid >> 6;
  const int wm = wid >> 1, wn = wid & 1;

  const int srow = tid >> 2, sq = tid & 3;
  const int arow0 = m0 + srow, arow1 = m0 + 64 + srow;
  int brow0 = n0 + srow;      if (brow0 > N - 1) brow0 = N - 1;
  int brow1 = n0 + 64 + srow; if (brow1 > N - 1) brow1 = N - 1;

  const u16* Bbf = (const u16*)Bsrc;
  const float* Bf32 = (const float*)Bsrc;
  u16* AsW = As + (size_t)(tid >> 6) * 512;
  u16* BsW = Bs + (size_t)(tid >> 6) * 512;

  f32x4 acc[4][4];
  f32x4 z = {0.f, 0.f, 0.f, 0.f};
#pragma unroll
  for (int a = 0; a < 4; ++a)
#pragma unroll
    for (int b = 0; b < 4; ++b) acc[a][b] = z;

  for (int k0 = 0; k0 < K; k0 += 32) {
    gld16(A + (size_t)arow0 * K + k0 + sq * 8, AsW);
    gld16(A + (size_t)arow1 * K + k0 + sq * 8, AsW + 2048);
    if (!BCVT) {
      gld16(Bbf + (size_t)brow0 * K + k0 + sq * 8, BsW);
      gld16(Bbf + (size_t)brow1 * K + k0 + sq * 8, BsW + 2048);
    } else {
      const float* s0 = Bf32 + (size_t)brow0 * K + k0 + sq * 8;
      const float* s1 = Bf32 + (size_t)brow1 * K + k0 + sq * 8;
      float4 x0 = *(const float4*)s0, y0 = *(const float4*)(s0 + 4);
      float4 x1 = *(const float4*)s1, y1 = *(const float4*)(s1 + 4);
      short8 v0, v1;
      v0[0]=(short)f2bf(x0.x); v0[1]=(short)f2bf(x0.y); v0[2]=(short)f2bf(x0.z); v0[3]=(short)f2bf(x0.w);
      v0[4]=(short)f2bf(y0.x); v0[5]=(short)f2bf(y0.y); v0[6]=(short)f2bf(y0.z); v0[7]=(short)f2bf(y0.w);
      v1[0]=(short)f2bf(x1.x); v1[1]=(short)f2bf(x1.y); v1[2]=(short)f2bf(x1.z); v1[3]=(short)f2bf(x1.w);
      v1[4]=(short)f2bf(y1.x); v1[5]=(short)f2bf(y1.y); v1[6]=(short)f2bf(y1.z); v1[7]=(short)f2bf(y1.w);
      *(short8*)&Bs[(size_t)tid * 8] = v0;
      *(short8*)&Bs[(size_t)tid * 8 + 2048] = v1;
    }
    __syncthreads();
    short8 af[4], bfr[4];
#pragma unroll
    for (int x = 0; x < 4; ++x) {
      int ar = wm * 64 + x * 16 + (l & 15);
      af[x] = *(const short8*)&As[ar * 32 + ((l >> 4) << 3)];
      int br = wn * 64 + x * 16 + (l & 15);
      bfr[x] = *(const short8*)&Bs[br * 32 + ((l >> 4) << 3)];
    }
#pragma unroll
    for (int mf = 0; mf < 4; ++mf)
#pragma unroll
      for (int nf = 0; nf < 4; ++nf)
        acc[mf][nf] = mfma16(af[mf], bfr[nf], acc[mf][nf]);
    __syncthreads();
  }

  if constexpr (EPI == 2) {
    u16* C = (u16*)Cout;
#pragma unroll
    for (int mf = 0; mf < 4; ++mf) {
      int rbase = m0 + wm * 64 + mf * 16 + ((l >> 4) << 2);
      float bvr[4];
#pragma unroll
      for (int j = 0; j < 4; ++j) bvr[j] = bias[rbase + j];
#pragma unroll
      for (int nf = 0; nf < 4; ++nf) {
        int cg = n0 + wn * 64 + nf * 16 + (l & 15);
#pragma unroll
        for (int j = 0; j < 4; ++j)
          C[(size_t)(rbase + j) * ldc + cg] = f2bf(acc[mf][nf][j] + bvr[j]);
      }
    }
  } else {
    float* C = (float*)Cout;
    int cg[4]; float bv[4]; bool ok[4];
#pragma unroll
    for (int nf = 0; nf < 4; ++nf) {
      cg[nf] = n0 + wn * 64 + nf * 16 + (l & 15);
      ok[nf] = (cg[nf] < N);
      bv[nf] = ok[nf] ? bias[cg[nf]] : 0.f;
    }
#pragma unroll
    for (int mf = 0; mf < 4; ++mf) {
#pragma unroll
      for (int j = 0; j < 4; ++j) {
        int r = m0 + wm * 64 + mf * 16 + ((l >> 4) << 2) + j;
        float e = 0.f;
#pragma unroll
        for (int nf = 0; nf < 4; ++nf) {
          float v = acc[mf][nf][j] + bv[nf];
          if (ok[nf]) { C[(size_t)r * ldc + cg[nf]] = v; e += __expf(v); }
        }
        e += __shfl_xor(e, 1, 16); e += __shfl_xor(e, 2, 16);
        e += __shfl_xor(e, 4, 16); e += __shfl_xor(e, 8, 16);
        if ((l & 15) == 0) atomicAdd(&rowsum[r], e);
      }
    }
  }
}

// ---------- cooperative 2-layer LSTM: specialized blocks + hierarchical barrier ----------
struct LstmArgs {
  const u16* G0T;      // [4H, M4] bf16: Wih0 @ X^T + b (gate-major)
  const float* Wih;    // [2,4H,H] f32
  const float* Whh;
  const float* bih, *bhh, *h0, *c0;
  u16* H0;             // [T+1, B, H]
  u16* H1;             // [B, T, H]
  u16* h1init;         // [B, H]
  float* out_hc;       // hT[2][B][H] then cT[2][B][H]
  unsigned* bar;       // >= 4KB zeroed
};

// bar layout (u32 idx): arrive[g] = g*32, master = 8*32, release[g] = (9+g)*32
DEVI void gridbar(unsigned* bar, unsigned& gen, int l, int grp) {
  __syncthreads();
  ++gen;
  __builtin_amdgcn_fence(__ATOMIC_RELEASE, "agent");
  if (l == 0) {
    unsigned* arr = bar + grp * 32;
    unsigned* master = bar + 8 * 32;
    unsigned* rel = bar + (9 + grp) * 32;
    unsigned prev = __hip_atomic_fetch_add(arr, 1u, __ATOMIC_RELAXED, __HIP_MEMORY_SCOPE_AGENT);
    if (prev == GRPSZ - 1u) {
      __hip_atomic_store(arr, 0u, __ATOMIC_RELAXED, __HIP_MEMORY_SCOPE_AGENT);
      unsigned mprev = __hip_atomic_fetch_add(master, 1u, __ATOMIC_RELEASE, __HIP_MEMORY_SCOPE_AGENT);
      if (mprev == 7u) {
        __hip_atomic_store(master, 0u, __ATOMIC_RELAXED, __HIP_MEMORY_SCOPE_AGENT);
#pragma unroll
        for (int g2 = 0; g2 < 8; ++g2)
          __hip_atomic_store(bar + (9 + g2) * 32, gen, __ATOMIC_RELEASE, __HIP_MEMORY_SCOPE_AGENT);
      }
    }
    while (__hip_atomic_load(rel, __ATOMIC_RELAXED, __HIP_MEMORY_SCOPE_AGENT) < gen)
      __builtin_amdgcn_s_sleep(1);
  }
  __syncthreads();
  __builtin_amdgcn_fence(__ATOMIC_ACQUIRE, "agent");
}

// stage one [1024] f32 row -> 2KB bf16 LDS row, XOR-swizzled by ((r&7)<<4)
DEVI void stage_row(const float* src, char* row, int sw) {
  for (int kk = 0; kk < 1024; kk += 8) {
    float4 x = *(const float4*)(src + kk);
    float4 y = *(const float4*)(src + kk + 4);
    short8 v;
    v[0]=(short)f2bf(x.x); v[1]=(short)f2bf(x.y); v[2]=(short)f2bf(x.z); v[3]=(short)f2bf(x.w);
    v[4]=(short)f2bf(y.x); v[5]=(short)f2bf(y.y); v[6]=(short)f2bf(y.z); v[7]=(short)f2bf(y.w);
    *(short8*)(row + ((kk * 2) ^ sw)) = v;
  }
}

DEVI short8 ldsB(const char* lds, int r, int kbyte) {
  return *(const short8*)(lds + (size_t)r * 2048 + (kbyte ^ ((r & 7) << 4)));
}

__global__ __launch_bounds__(64, 1) void lstm_coop(LstmArgs A) {
  extern __shared__ char smem[];
  const int wg = blockIdx.x, l = threadIdx.x;
  const int grp = wg & 7;
  const int l15 = l & 15, lq = l >> 4;
  unsigned gen = 0;

  if (wg < 64) {
    // ================= layer 0: 16 units, rows r = gate*16 + unit =================
    char* WL = smem;                         // Whh0 [64][2048B]
    float* gl = (float*)(smem + 131072);     // gates [64][36]
    const int j0 = wg << 4;
    {
      const int r = l;
      const int grow = ((r >> 4) << 10) + j0 + (r & 15);
      stage_row(A.Whh + (size_t)grow * HSZ, WL + (size_t)r * 2048, (r & 7) << 4);
    }
    {
      int e = wg * 512 + l * 8;
#pragma unroll
      for (int i = 0; i < 8; ++i) A.H0[e + i] = f2bf(A.h0[e + i]);
    }
    const int uu = l15;
    float cst[8];
#pragma unroll
    for (int p = 0; p < 8; ++p) {
      int b = lq + (p << 2);
      cst[p] = A.c0[(size_t)b * HSZ + j0 + uu];
    }
    gridbar(A.bar, gen, l, grp);

    for (int t = 0; t < TSZ; ++t) {
      f32x4 acc[4][2];
#pragma unroll
      for (int tr = 0; tr < 4; ++tr) {
        const u16* g0p = A.G0T + ((size_t)(tr << 10) + j0 + l15) * M4 + t * 32 + (lq << 2);
#pragma unroll
        for (int p = 0; p < 2; ++p) {
          ushort4 gv = *(const ushort4*)(g0p + p * 16);
          acc[tr][p][0] = bf2f(gv.x); acc[tr][p][1] = bf2f(gv.y);
          acc[tr][p][2] = bf2f(gv.z); acc[tr][p][3] = bf2f(gv.w);
        }
      }
      const u16* hprev = A.H0 + (size_t)t * (BSZ * HSZ);
      const u16* hr0 = hprev + (size_t)l15 * HSZ + (lq << 3);
      const u16* hr1 = hr0 + 16 * HSZ;
      short8 ab[2][16];
#pragma unroll
      for (int k = 0; k < 8; ++k) {
        ab[0][k]     = *(const short8*)(hr0 + k * 32);
        ab[0][8 + k] = *(const short8*)(hr1 + k * 32);
      }
#pragma unroll
      for (int c = 0; c < 4; ++c) {
        const int cb = c & 1, nb = cb ^ 1;
        if (c < 3) {
#pragma unroll
          for (int k = 0; k < 8; ++k) {
            ab[nb][k]     = *(const short8*)(hr0 + (c + 1) * 256 + k * 32);
            ab[nb][8 + k] = *(const short8*)(hr1 + (c + 1) * 256 + k * 32);
          }
        }
#pragma unroll
        for (int k = 0; k < 8; ++k) {
          const int kbyte = ((c << 3) + k) * 64 + (lq << 4);
#pragma unroll
          for (int tr = 0; tr < 4; ++tr) {
            short8 bf = ldsB(WL, (tr << 4) + l15, kbyte);
            acc[tr][0] = mfma16(ab[cb][k], bf, acc[tr][0]);
            acc[tr][1] = mfma16(ab[cb][8 + k], bf, acc[tr][1]);
          }
        }
      }
#pragma unroll
      for (int tr = 0; tr < 4; ++tr)
#pragma unroll
        for (int p = 0; p < 2; ++p)
          *(f32x4*)&gl[((tr << 4) + l15) * 36 + (p << 4) + (lq << 2)] = acc[tr][p];
      __syncthreads();
      const bool last = (t == TSZ - 1);
      u16* hnext = A.H0 + (size_t)(t + 1) * (BSZ * HSZ);
#pragma unroll
      for (int p = 0; p < 8; ++p) {
        int b = lq + (p << 2);
        float gi = gl[uu * 36 + b];
        float gf = gl[(16 + uu) * 36 + b];
        float gg = gl[(32 + uu) * 36 + b];
        float go = gl[(48 + uu) * 36 + b];
        float i_ = sigm(gi), f_ = sigm(gf), g_ = tanh_fast(gg), o_ = sigm(go);
        float c_ = f_ * cst[p] + i_ * g_;
        cst[p] = c_;
        float h_ = o_ * tanh_fast(c_);
        hnext[(size_t)b * HSZ + j0 + uu] = f2bf(h_);
        if (last) {
          A.out_hc[(size_t)b * HSZ + j0 + uu] = h_;
          A.out_hc[2 * BSZ * HSZ + (size_t)b * HSZ + j0 + uu] = c_;
        }
      }
      gridbar(A.bar, gen, l, grp);
    }
  } else {
    // ================= layer 1: 8 units, rows r = gate*8 + unit =================
    char* WxL = smem;                        // Wih1 [32][2048B]
    char* WhL = smem + 65536;                // Whh1 [32][2048B]
    float* gl = (float*)(smem + 131072);     // gates [32][36]
    const int lw = wg - 64;
    const int j1 = lw << 3;
    {
      const int r = l & 31;
      const int grow = FH + ((r >> 3) << 10) + j1 + (r & 7);
      const float* base = (l >> 5) ? A.Whh : A.Wih;
      char* dst = ((l >> 5) ? WhL : WxL) + (size_t)r * 2048;
      stage_row(base + (size_t)grow * HSZ, dst, (r & 7) << 4);
    }
    {
      int e = lw * 256 + l * 4;
#pragma unroll
      for (int i = 0; i < 4; ++i) A.h1init[e + i] = f2bf(A.h0[BSZ * HSZ + e + i]);
    }
    float bv[2];
#pragma unroll
    for (int tr = 0; tr < 2; ++tr) {
      int r = (tr << 4) + l15;
      int grow = FH + ((r >> 3) << 10) + j1 + (r & 7);
      bv[tr] = A.bih[grow] + A.bhh[grow];
    }
    const int uu = l & 7;
    const int bb = l >> 3;     // 0..7
    float cst[4];
#pragma unroll
    for (int p = 0; p < 4; ++p) {
      int b = bb + (p << 3);
      cst[p] = A.c0[BSZ * HSZ + (size_t)b * HSZ + j1 + uu];
    }
    gridbar(A.bar, gen, l, grp);

    for (int tau = 0; tau <= TSZ; ++tau) {
      if (tau >= 1) {
        const int t = tau - 1;
        f32x4 aX[2][2], aH[2][2];
#pragma unroll
        for (int tr = 0; tr < 2; ++tr)
#pragma unroll
          for (int p = 0; p < 2; ++p) {
            aX[tr][p][0] = bv[tr]; aX[tr][p][1] = bv[tr];
            aX[tr][p][2] = bv[tr]; aX[tr][p][3] = bv[tr];
            aH[tr][p][0] = 0.f; aH[tr][p][1] = 0.f; aH[tr][p][2] = 0.f; aH[tr][p][3] = 0.f;
          }
        const u16* x1 = A.H0 + (size_t)(t + 1) * (BSZ * HSZ);
        const u16* xr0 = x1 + (size_t)l15 * HSZ + (lq << 3);
        const u16* xr1 = xr0 + 16 * HSZ;
        const u16* hp = (t == 0) ? A.h1init : A.H1 + (size_t)(t - 1) * HSZ;
        const size_t hstr = (t == 0) ? (size_t)HSZ : (size_t)TSZ * HSZ;
        const u16* hb0 = hp + (size_t)l15 * hstr + (lq << 3);
        const u16* hb1 = hp + (size_t)(l15 + 16) * hstr + (lq << 3);
        short8 xb[2][8], hb[2][8];
#pragma unroll
        for (int k = 0; k < 4; ++k) {
          xb[0][k]     = *(const short8*)(xr0 + k * 32);
          xb[0][4 + k] = *(const short8*)(xr1 + k * 32);
          hb[0][k]     = *(const short8*)(hb0 + k * 32);
          hb[0][4 + k] = *(const short8*)(hb1 + k * 32);
        }
#pragma unroll
        for (int c = 0; c < 8; ++c) {
          const int cb = c & 1, nb = cb ^ 1;
          if (c < 7) {
#pragma unroll
            for (int k = 0; k < 4; ++k) {
              xb[nb][k]     = *(const short8*)(xr0 + (c + 1) * 128 + k * 32);
              xb[nb][4 + k] = *(const short8*)(xr1 + (c + 1) * 128 + k * 32);
              hb[nb][k]     = *(const short8*)(hb0 + (c + 1) * 128 + k * 32);
              hb[nb][4 + k] = *(const short8*)(hb1 + (c + 1) * 128 + k * 32);
            }
          }
#pragma unroll
          for (int k = 0; k < 4; ++k) {
            const int kbyte = ((c << 2) + k) * 64 + (lq << 4);
            short8 bx0 = ldsB(WxL, l15, kbyte);
            short8 bx1 = ldsB(WxL, 16 + l15, kbyte);
            short8 bh0 = ldsB(WhL, l15, kbyte);
            short8 bh1 = ldsB(WhL, 16 + l15, kbyte);
            aX[0][0] = mfma16(xb[cb][k], bx0, aX[0][0]);
            aX[0][1] = mfma16(xb[cb][4 + k], bx0, aX[0][1]);
            aX[1][0] = mfma16(xb[cb][k], bx1, aX[1][0]);
            aX[1][1] = mfma16(xb[cb][4 + k], bx1, aX[1][1]);
            aH[0][0] = mfma16(hb[cb][k], bh0, aH[0][0]);
            aH[0][1] = mfma16(hb[cb][4 + k], bh0, aH[0][1]);
            aH[1][0] = mfma16(hb[cb][k], bh1, aH[1][0]);
            aH[1][1] = mfma16(hb[cb][4 + k], bh1, aH[1][1]);
          }
        }
#pragma unroll
        for (int tr = 0; tr < 2; ++tr)
#pragma unroll
          for (int p = 0; p < 2; ++p) {
            f32x4 s = aX[tr][p] + aH[tr][p];
            *(f32x4*)&gl[((tr << 4) + l15) * 36 + (p << 4) + (lq << 2)] = s;
          }
        __syncthreads();
        const bool last = (t == TSZ - 1);
#pragma unroll
        for (int p = 0; p < 4; ++p) {
          int b = bb + (p << 3);
          float gi = gl[uu * 36 + b];
          float gf = gl[(8 + uu) * 36 + b];
          float gg = gl[(16 + uu) * 36 + b];
          float go = gl[(24 + uu) * 36 + b];
          float i_ = sigm(gi), f_ = sigm(gf), g_ = tanh_fast(gg), o_ = sigm(go);
          float c_ = f_ * cst[p] + i_ * g_;
          cst[p] = c_;
          float h_ = o_ * tanh_fast(c_);
          A.H1[(size_t)b * (TSZ * HSZ) + (size_t)t * HSZ + j1 + uu] = f2bf(h_);
          if (last) {
            A.out_hc[BSZ * HSZ + (size_t)b * HSZ + j1 + uu] = h_;
            A.out_hc[3 * BSZ * HSZ + (size_t)b * HSZ + j1 + uu] = c_;
          }
        }
      }
      if (tau < TSZ) gridbar(A.bar, gen, l, grp);
    }
  }
}

// ---------- logsumexp finish ----------
__global__ void lse_kernel(float* __restrict__ rowsum, int n) {
  int i = blockIdx.x * 256 + threadIdx.x;
  if (i < n) rowsum[i] = logf(rowsum[i]);
}

__global__ __launch_bounds__(256) void lsm_finish(float* __restrict__ C,
                                                  const float* __restrict__ lse, int Vd) {
  int row = blockIdx.y;
  int col = blockIdx.x * 256 + threadIdx.x;
  if (col < Vd) {
    float s = lse[row];
    size_t idx = (size_t)row * Vd + col;
    C[idx] -= s;
  }
}

// ---------- launcher ----------
extern "C" void kernel_launch(void* const* d_in, const int* in_sizes, int n_in,
                              void* d_out, int out_size, void* d_ws, size_t ws_size,
                              hipStream_t stream) {
  const int* tokens = (const int*)d_in[0];
  const float* emb = (const float*)d_in[1];
  const float* Wih = (const float*)d_in[2];
  const float* Whh = (const float*)d_in[3];
  const float* bih = (const float*)d_in[4];
  const float* bhh = (const float*)d_in[5];
  const float* Wout = (const float*)d_in[6];
  const float* bout = (const float*)d_in[7];
  const float* h0 = (const float*)d_in[8];
  const float* c0 = (const float*)d_in[9];
  float* out = (float*)d_out;

  char* w = (char*)d_ws;
  size_t o = 0;
  u16* Xbf = (u16*)(w + o);    o += (size_t)M4 * HSZ * 2;
  u16* Wih0bf = (u16*)(w + o); o += (size_t)FH * HSZ * 2;
  u16* G0T = (u16*)(w + o);    o += (size_t)FH * M4 * 2;
  u16* H0 = (u16*)(w + o);     o += (size_t)(TSZ + 1) * BSZ * HSZ * 2;
  u16* H1 = (u16*)(w + o);     o += (size_t)BSZ * TSZ * HSZ * 2;
  u16* h1init = (u16*)(w + o); o += (size_t)BSZ * HSZ * 2;
  float* bias0 = (float*)(w + o);  o += FH * 4;
  float* rowsum = (float*)(w + o); o += M4 * 4;
  unsigned* bar = (unsigned*)(w + o); o += 4096;
  u16* Woutbf = (u16*)(w + o);
  size_t need_full = o + (size_t)VSZ * HSZ * 2;
  const bool bcvt = (ws_size < need_full);

  prep_misc<<<16, 256, 0, stream>>>(bih, bhh, bias0, rowsum, bar);
  cvt_bf16<<<2048, 256, 0, stream>>>(Wih, Wih0bf, FH * HSZ / 4);
  if (!bcvt)
    cvt_bf16<<<4096, 256, 0, stream>>>(Wout, Woutbf, (int)((size_t)VSZ * HSZ / 4));
  embed_kernel<<<M4, 256, 0, stream>>>(tokens, emb, Xbf);
  // G0T[4H][M4] = Wih0 @ X^T + (b_ih0 + b_hh0)  (bias per row)
  gemm_bt<2, false><<<32 * 32, 256, 0, stream>>>(Wih0bf, Xbf, G0T, bias0, nullptr,
                                                 32, 32, M4, HSZ, M4);

  LstmArgs la{G0T, Wih, Whh, bih, bhh, h0, c0, H0, H1, h1init,
              out + (size_t)OUT_LOGP, bar};
  void* kargs[] = {&la};
  hipFuncSetAttribute((const void*)lstm_coop, hipFuncAttributeMaxDynamicSharedMemorySize, 140288);
  hipLaunchCooperativeKernel((const void*)lstm_coop, dim3(NBLK), dim3(64), kargs, 140288, stream);

  const int nn = (VSZ + 127) / 128;  // 393
  if (!bcvt)
    gemm_bt<1, false><<<32 * nn, 256, 0, stream>>>(H1, Woutbf, out, bout, rowsum,
                                                   32, nn, VSZ, HSZ, VSZ);
  else
    gemm_bt<1, true><<<32 * nn, 256, 0, stream>>>(H1, Wout, out, bout, rowsum,
                                                  32, nn, VSZ, HSZ, VSZ);

  lse_kernel<<<16, 256, 0, stream>>>(rowsum, M4);
  lsm_finish<<<dim3((VSZ + 255) / 256, M4), 256, 0, stream>>>(out, rowsum, VSZ);
}

// Round 4
// 2477.573 us; speedup vs baseline: 2.2284x; 1.5442x over previous
//
#include <hip/hip_runtime.h>
#include <cstdint>
#include <cstddef>

#define DEVI __device__ __forceinline__

typedef __attribute__((ext_vector_type(8))) short short8;
typedef __attribute__((ext_vector_type(4))) float f32x4;
using u16 = unsigned short;

constexpr int BSZ = 32, TSZ = 128, VSZ = 50257, HSZ = 1024;
constexpr int M4 = BSZ * TSZ;          // 4096 rows
constexpr int FH = 4 * HSZ;            // 4096 gate rows
constexpr long long OUT_LOGP = (long long)M4 * VSZ;
constexpr int NWRK = 192;              // 64 layer0 + 128 layer1 worker blocks
constexpr int NBLK = NWRK + 1;         // + master poll block
constexpr int LDSB = 147584;           // dynamic LDS bytes (< known-risky 160KB)

// ---------- small helpers ----------
DEVI u16 f2bf(float f) {
  unsigned u = __float_as_uint(f);
  unsigned r = (u + 0x7fffu + ((u >> 16) & 1u)) >> 16;
  return (u16)r;
}
DEVI float bf2f(u16 u) { return __uint_as_float(((unsigned)u) << 16); }
DEVI float sigm(float x) { return 1.f / (1.f + __expf(-x)); }
DEVI float tanh_fast(float x) { return 1.f - 2.f / (1.f + __expf(2.f * x)); }

DEVI f32x4 mfma16(short8 a, short8 b, f32x4 c) {
  return __builtin_amdgcn_mfma_f32_16x16x32_bf16(a, b, c, 0, 0, 0);
}

DEVI void gld16(const void* g, void* l) {
  auto gp = (const __attribute__((address_space(1))) unsigned int*)g;
  auto lp = (__attribute__((address_space(3))) unsigned int*)l;
  __builtin_amdgcn_global_load_lds(gp, lp, 16, 0, 0);
}

// ---------- SAFE coherent primitives ----------
// Every VMEM op begins AND completes (vmcnt-drained) inside a single asm block:
// no in-flight register lifetimes escape an asm boundary (no spill/WAR hazards).
DEVI void cohld16x16(const u16* base, short8 (&d)[16]) {
  asm volatile(
      "global_load_dwordx4 %0, %16, off sc0 sc1\n\t"
      "global_load_dwordx4 %1, %16, off offset:64 sc0 sc1\n\t"
      "global_load_dwordx4 %2, %16, off offset:128 sc0 sc1\n\t"
      "global_load_dwordx4 %3, %16, off offset:192 sc0 sc1\n\t"
      "global_load_dwordx4 %4, %16, off offset:256 sc0 sc1\n\t"
      "global_load_dwordx4 %5, %16, off offset:320 sc0 sc1\n\t"
      "global_load_dwordx4 %6, %16, off offset:384 sc0 sc1\n\t"
      "global_load_dwordx4 %7, %16, off offset:448 sc0 sc1\n\t"
      "global_load_dwordx4 %8, %16, off offset:512 sc0 sc1\n\t"
      "global_load_dwordx4 %9, %16, off offset:576 sc0 sc1\n\t"
      "global_load_dwordx4 %10, %16, off offset:640 sc0 sc1\n\t"
      "global_load_dwordx4 %11, %16, off offset:704 sc0 sc1\n\t"
      "global_load_dwordx4 %12, %16, off offset:768 sc0 sc1\n\t"
      "global_load_dwordx4 %13, %16, off offset:832 sc0 sc1\n\t"
      "global_load_dwordx4 %14, %16, off offset:896 sc0 sc1\n\t"
      "global_load_dwordx4 %15, %16, off offset:960 sc0 sc1\n\t"
      "s_waitcnt vmcnt(0)"
      : "=&v"(d[0]), "=&v"(d[1]), "=&v"(d[2]), "=&v"(d[3]),
        "=&v"(d[4]), "=&v"(d[5]), "=&v"(d[6]), "=&v"(d[7]),
        "=&v"(d[8]), "=&v"(d[9]), "=&v"(d[10]), "=&v"(d[11]),
        "=&v"(d[12]), "=&v"(d[13]), "=&v"(d[14]), "=&v"(d[15])
      : "v"(base)
      : "memory");
}
DEVI void cohst2_u16(u16* p0, u16 v0, u16* p1, u16 v1) {
  asm volatile(
      "global_store_short %0, %2, off sc0 sc1\n\t"
      "global_store_short %1, %3, off sc0 sc1\n\t"
      "s_waitcnt vmcnt(0)"
      :: "v"(p0), "v"(p1), "v"((unsigned)v0), "v"((unsigned)v1)
      : "memory");
}
DEVI void cohst1_u16(u16* p0, u16 v0) {
  asm volatile(
      "global_store_short %0, %1, off sc0 sc1\n\t"
      "s_waitcnt vmcnt(0)"
      :: "v"(p0), "v"((unsigned)v0)
      : "memory");
}
DEVI void flagst(unsigned* p, unsigned v) {
  __hip_atomic_store(p, v, __ATOMIC_RELAXED, __HIP_MEMORY_SCOPE_AGENT);
}
DEVI unsigned flagld(const unsigned* p) {
  return __hip_atomic_load(p, __ATOMIC_RELAXED, __HIP_MEMORY_SCOPE_AGENT);
}

// ---------- prep kernels ----------
__global__ void prep_misc(const float* __restrict__ bih, const float* __restrict__ bhh,
                          float* __restrict__ bias0, float* __restrict__ rowsum,
                          unsigned* __restrict__ bar) {
  int i = blockIdx.x * 256 + threadIdx.x;
  if (i < FH) { bias0[i] = bih[i] + bhh[i]; rowsum[i] = 0.f; }
  if (i < 1024) bar[i] = 0u;
}

__global__ void prep_h(const float* __restrict__ h0, u16* __restrict__ H0,
                       u16* __restrict__ h1init) {
  int i = blockIdx.x * 256 + threadIdx.x;   // 0..32767
  H0[i] = f2bf(h0[i]);
  h1init[i] = f2bf(h0[BSZ * HSZ + i]);
}

__global__ void cvt_bf16(const float* __restrict__ src, u16* __restrict__ dst, int n4) {
  int i = blockIdx.x * blockDim.x + threadIdx.x;
  int stride = gridDim.x * blockDim.x;
  for (; i < n4; i += stride) {
    float4 v = ((const float4*)src)[i];
    ushort4 o; o.x = f2bf(v.x); o.y = f2bf(v.y); o.z = f2bf(v.z); o.w = f2bf(v.w);
    ((ushort4*)dst)[i] = o;
  }
}

__global__ __launch_bounds__(256) void embed_kernel(const int* __restrict__ tok,
                                                    const float* __restrict__ emb,
                                                    u16* __restrict__ X) {
  int m = blockIdx.x;                // m = t*32 + b
  int t = m >> 5, b = m & 31;
  int token = tok[b * TSZ + t];
  const float4* src = (const float4*)(emb + (size_t)token * HSZ);
  int i = threadIdx.x;
  float4 v = src[i];
  ushort4 o; o.x = f2bf(v.x); o.y = f2bf(v.y); o.z = f2bf(v.z); o.w = f2bf(v.w);
  *(ushort4*)(X + (size_t)m * HSZ + i * 4) = o;
}

// ---------- 128x128 bf16 MFMA GEMM: C = A * B^T ----------
// EPI 1: C f32 + bias[col] + per-row sum(exp) atomics (vocab projection).
// EPI 2: C bf16 + bias[row] (G0T = Wih0 @ X^T + b).
template <int EPI, bool BCVT>
__global__ __launch_bounds__(256) void gemm_bt(const u16* __restrict__ A,
                                               const void* __restrict__ Bsrc,
                                               void* __restrict__ Cout,
                                               const float* __restrict__ bias,
                                               float* __restrict__ rowsum,
                                               int nm, int nn, int N, int K, int ldc) {
  __shared__ u16 As[128 * 32];
  __shared__ u16 Bs[128 * 32];
  const int tid = threadIdx.x;
  int gsz = nm * nn;
  int id = blockIdx.x;
  int wg = ((gsz & 7) == 0) ? (id % 8) * (gsz >> 3) + (id >> 3) : id;
  const int bm = wg % nm, bn = wg / nm;
  const int m0 = bm * 128, n0 = bn * 128;
  const int l = tid & 63, wid = tid >> 6;
  const int wm = wid >> 1, wn = wid & 1;

  const int srow = tid >> 2, sq = tid & 3;
  const int arow0 = m0 + srow, arow1 = m0 + 64 + srow;
  int brow0 = n0 + srow;      if (brow0 > N - 1) brow0 = N - 1;
  int brow1 = n0 + 64 + srow; if (brow1 > N - 1) brow1 = N - 1;

  const u16* Bbf = (const u16*)Bsrc;
  const float* Bf32 = (const float*)Bsrc;
  u16* AsW = As + (size_t)(tid >> 6) * 512;
  u16* BsW = Bs + (size_t)(tid >> 6) * 512;

  f32x4 acc[4][4];
  f32x4 z = {0.f, 0.f, 0.f, 0.f};
#pragma unroll
  for (int a = 0; a < 4; ++a)
#pragma unroll
    for (int b = 0; b < 4; ++b) acc[a][b] = z;

  for (int k0 = 0; k0 < K; k0 += 32) {
    gld16(A + (size_t)arow0 * K + k0 + sq * 8, AsW);
    gld16(A + (size_t)arow1 * K + k0 + sq * 8, AsW + 2048);
    if (!BCVT) {
      gld16(Bbf + (size_t)brow0 * K + k0 + sq * 8, BsW);
      gld16(Bbf + (size_t)brow1 * K + k0 + sq * 8, BsW + 2048);
    } else {
      const float* s0 = Bf32 + (size_t)brow0 * K + k0 + sq * 8;
      const float* s1 = Bf32 + (size_t)brow1 * K + k0 + sq * 8;
      float4 x0 = *(const float4*)s0, y0 = *(const float4*)(s0 + 4);
      float4 x1 = *(const float4*)s1, y1 = *(const float4*)(s1 + 4);
      short8 v0, v1;
      v0[0]=(short)f2bf(x0.x); v0[1]=(short)f2bf(x0.y); v0[2]=(short)f2bf(x0.z); v0[3]=(short)f2bf(x0.w);
      v0[4]=(short)f2bf(y0.x); v0[5]=(short)f2bf(y0.y); v0[6]=(short)f2bf(y0.z); v0[7]=(short)f2bf(y0.w);
      v1[0]=(short)f2bf(x1.x); v1[1]=(short)f2bf(x1.y); v1[2]=(short)f2bf(x1.z); v1[3]=(short)f2bf(x1.w);
      v1[4]=(short)f2bf(y1.x); v1[5]=(short)f2bf(y1.y); v1[6]=(short)f2bf(y1.z); v1[7]=(short)f2bf(y1.w);
      *(short8*)&Bs[(size_t)tid * 8] = v0;
      *(short8*)&Bs[(size_t)tid * 8 + 2048] = v1;
    }
    __syncthreads();
    short8 af[4], bfr[4];
#pragma unroll
    for (int x = 0; x < 4; ++x) {
      int ar = wm * 64 + x * 16 + (l & 15);
      af[x] = *(const short8*)&As[ar * 32 + ((l >> 4) << 3)];
      int br = wn * 64 + x * 16 + (l & 15);
      bfr[x] = *(const short8*)&Bs[br * 32 + ((l >> 4) << 3)];
    }
#pragma unroll
    for (int mf = 0; mf < 4; ++mf)
#pragma unroll
      for (int nf = 0; nf < 4; ++nf)
        acc[mf][nf] = mfma16(af[mf], bfr[nf], acc[mf][nf]);
    __syncthreads();
  }

  if constexpr (EPI == 2) {
    u16* C = (u16*)Cout;
#pragma unroll
    for (int mf = 0; mf < 4; ++mf) {
      int rbase = m0 + wm * 64 + mf * 16 + ((l >> 4) << 2);
      float bvr[4];
#pragma unroll
      for (int j = 0; j < 4; ++j) bvr[j] = bias[rbase + j];
#pragma unroll
      for (int nf = 0; nf < 4; ++nf) {
        int cg = n0 + wn * 64 + nf * 16 + (l & 15);
#pragma unroll
        for (int j = 0; j < 4; ++j)
          C[(size_t)(rbase + j) * ldc + cg] = f2bf(acc[mf][nf][j] + bvr[j]);
      }
    }
  } else {
    float* C = (float*)Cout;
    int cg[4]; float bv[4]; bool ok[4];
#pragma unroll
    for (int nf = 0; nf < 4; ++nf) {
      cg[nf] = n0 + wn * 64 + nf * 16 + (l & 15);
      ok[nf] = (cg[nf] < N);
      bv[nf] = ok[nf] ? bias[cg[nf]] : 0.f;
    }
#pragma unroll
    for (int mf = 0; mf < 4; ++mf) {
#pragma unroll
      for (int j = 0; j < 4; ++j) {
        int r = m0 + wm * 64 + mf * 16 + ((l >> 4) << 2) + j;
        float e = 0.f;
#pragma unroll
        for (int nf = 0; nf < 4; ++nf) {
          float v = acc[mf][nf][j] + bv[nf];
          if (ok[nf]) { C[(size_t)r * ldc + cg[nf]] = v; e += __expf(v); }
        }
        e += __shfl_xor(e, 1, 16); e += __shfl_xor(e, 2, 16);
        e += __shfl_xor(e, 4, 16); e += __shfl_xor(e, 8, 16);
        if ((l & 15) == 0) atomicAdd(&rowsum[r], e);
      }
    }
  }
}

// ---------- cooperative 2-layer LSTM ----------
// Sync: zero fences, zero RMW. Data moves via sc0sc1 (LLC-coherent) asm groups
// that fully drain inside each asm block. Flags via relaxed agent atomics.
//   layer0 iter t: wait rel>=t (t>0); compute h0_t; flag = t+1.
//   layer1 iter t: wait rel>=t+1; compute h1_t; flag = t+2 (initial flag 1).
//   master: for g=1..128: poll all 192 flags >= g; store 8 release words = g.
struct LstmArgs {
  const u16* G0T;      // [4H, M4] bf16: Wih0 @ X^T + (b_ih0+b_hh0), gate-major
  const float* Wih;    // [2,4H,H] f32
  const float* Whh;
  const float* bih, *bhh, *c0;
  u16* H0;             // [T+1, B, H]
  u16* H1;             // [B, T, H]
  const u16* h1init;   // [B, H]
  float* out_hc;       // hT[2][B][H] then cT[2][B][H]
  unsigned* bar;       // flags [0..191], release words at 256 + g*32
};

DEVI void waitrel(const unsigned* rel, unsigned g, int tid) {
  if (tid == 0) {
    while (flagld(rel) < g) __builtin_amdgcn_s_sleep(1);
  }
  __syncthreads();
}

// stage a 256-float quarter of a [1024] f32 row into a 2KB bf16 LDS row (XOR-swizzled)
DEVI void stage_row_q(const float* src, char* row, int sw, int q) {
  for (int kk = 0; kk < 256; kk += 8) {
    float4 x = *(const float4*)(src + kk);
    float4 y = *(const float4*)(src + kk + 4);
    short8 v;
    v[0]=(short)f2bf(x.x); v[1]=(short)f2bf(x.y); v[2]=(short)f2bf(x.z); v[3]=(short)f2bf(x.w);
    v[4]=(short)f2bf(y.x); v[5]=(short)f2bf(y.y); v[6]=(short)f2bf(y.z); v[7]=(short)f2bf(y.w);
    const int kbyte = (q * 256 + kk) * 2;
    *(short8*)(row + (kbyte ^ sw)) = v;
  }
}

DEVI short8 ldsB(const char* lds, int r, int kbyte) {
  return *(const short8*)(lds + (size_t)r * 2048 + (kbyte ^ ((r & 7) << 4)));
}

DEVI void part_wr(float* part, int w, int row, int colb, f32x4 v) {
  *(f32x4*)&part[(w << 10) + (row << 5) + (colb ^ ((row & 7) << 2))] = v;
}

__global__ __launch_bounds__(256, 1) void lstm_coop(LstmArgs A) {
  extern __shared__ char smem[];
  const int wg = blockIdx.x, tid = threadIdx.x;
  const int wv = tid >> 6, l = tid & 63;
  const int l15 = l & 15, lq = l >> 4;

  if (wg < 64) {
    // ===== layer 0: 16 units/block. wave = (unit-pair p = wv>>1) x (K-half kh = wv&1)
    char* WL = smem;                        // [2 pairs][32 rows][2048B] Whh0
    float* part = (float*)(smem + 131072);  // [4 waves][32][32] f32
    const int j0 = wg << 4;
    {
      const int rr = tid >> 2, q = tid & 3;     // rr = p*32 + r', r' = gate*8+u'
      const int p = rr >> 5, rp = rr & 31;
      const int grow = ((rp >> 3) << 10) + j0 + (p << 3) + (rp & 7);
      stage_row_q(A.Whh + (size_t)grow * HSZ + q * 256, WL + (size_t)rr * 2048,
                  (rr & 7) << 4, q);
    }
    const int uu = tid & 15, bb = tid >> 4;     // ew cells (uu,bb), (uu,bb+16)
    float cst[2];
    cst[0] = A.c0[(size_t)bb * HSZ + j0 + uu];
    cst[1] = A.c0[(size_t)(bb + 16) * HSZ + j0 + uu];
    __syncthreads();
    unsigned* myflag = A.bar + wg;
    const unsigned* rel = A.bar + 256 + (wg & 7) * 32;
    const int p = wv >> 1, kh = wv & 1;

    for (int t = 0; t < TSZ; ++t) {
      if (t > 0) waitrel(rel, (unsigned)t, tid);
      const u16* hprev = A.H0 + (size_t)t * (BSZ * HSZ);
      const u16* hb0 = hprev + (size_t)l15 * HSZ + (kh << 9) + (lq << 3);
      short8 a0[16], a1[16];
      cohld16x16(hb0, a0);
      cohld16x16(hb0 + 16 * HSZ, a1);
      __builtin_amdgcn_sched_barrier(0);
      f32x4 acc[2][2];
      { f32x4 z = {0.f,0.f,0.f,0.f}; acc[0][0]=z; acc[0][1]=z; acc[1][0]=z; acc[1][1]=z; }
#pragma unroll
      for (int k = 0; k < 16; ++k) {
        const int kbyte = (((kh << 4) + k) << 6) + (lq << 4);
        short8 b0f = ldsB(WL, (p << 5) + l15, kbyte);
        short8 b1f = ldsB(WL, (p << 5) + 16 + l15, kbyte);
        acc[0][0] = mfma16(a0[k], b0f, acc[0][0]);
        acc[0][1] = mfma16(a1[k], b0f, acc[0][1]);
        acc[1][0] = mfma16(a0[k], b1f, acc[1][0]);
        acc[1][1] = mfma16(a1[k], b1f, acc[1][1]);
      }
#pragma unroll
      for (int tr = 0; tr < 2; ++tr)
#pragma unroll
        for (int hf = 0; hf < 2; ++hf)
          part_wr(part, wv, (tr << 4) + l15, (hf << 4) + (lq << 2), acc[tr][hf]);
      __syncthreads();
      const bool last = (t == TSZ - 1);
      u16* hnext = A.H0 + (size_t)(t + 1) * (BSZ * HSZ);
      const int pw = (uu >> 3) << 1, u8 = uu & 7, csw = u8 << 2;
      const int col = t * 32;
      u16 hv[2];
#pragma unroll
      for (int pp = 0; pp < 2; ++pp) {
        const int b = bb + (pp << 4);
        const int bs = b ^ csw;
        float gi = 0.f, gf = 0.f, gg = 0.f, go = 0.f;
#pragma unroll
        for (int w2 = pw; w2 < pw + 2; ++w2) {
          const float* pb = part + (w2 << 10);
          gi += pb[(u8 << 5) + bs];
          gf += pb[((8 + u8) << 5) + bs];
          gg += pb[((16 + u8) << 5) + bs];
          go += pb[((24 + u8) << 5) + bs];
        }
        gi += bf2f(A.G0T[(size_t)(j0 + uu) * M4 + col + b]);
        gf += bf2f(A.G0T[(size_t)(1024 + j0 + uu) * M4 + col + b]);
        gg += bf2f(A.G0T[(size_t)(2048 + j0 + uu) * M4 + col + b]);
        go += bf2f(A.G0T[(size_t)(3072 + j0 + uu) * M4 + col + b]);
        float i_ = sigm(gi), f_ = sigm(gf), g_ = tanh_fast(gg), o_ = sigm(go);
        float c_ = f_ * cst[pp] + i_ * g_;
        cst[pp] = c_;
        float h_ = o_ * tanh_fast(c_);
        hv[pp] = f2bf(h_);
        if (last) {
          A.out_hc[(size_t)b * HSZ + j0 + uu] = h_;
          A.out_hc[2 * BSZ * HSZ + (size_t)b * HSZ + j0 + uu] = c_;
        }
      }
      cohst2_u16(hnext + (size_t)bb * HSZ + j0 + uu, hv[0],
                 hnext + (size_t)(bb + 16) * HSZ + j0 + uu, hv[1]);
      __syncthreads();
      if (tid == 0) flagst(myflag, (unsigned)(t + 1));
    }
  } else if (wg < NWRK) {
    // ===== layer 1: 8 units/block. wave = (role wv>>1: 0=x,1=h) x (K-half kh = wv&1)
    char* WxL = smem;                         // [32 rows][2048B] Wih1
    char* WhL = smem + 65536;                 // [32 rows][2048B] Whh1
    float* part = (float*)(smem + 131072);    // [4 waves][32][32] f32
    float* biasL = (float*)(smem + 147456);   // [32]
    const int lw = wg - 64;
    const int j1 = lw << 3;
    {
      const int rr = tid >> 2, q = tid & 3;
      const int r = rr & 31;                   // r = gate*8 + u'
      const int grow = FH + ((r >> 3) << 10) + j1 + (r & 7);
      const float* base = (rr >= 32) ? A.Whh : A.Wih;
      char* dst = ((rr >= 32) ? WhL : WxL) + (size_t)r * 2048;
      stage_row_q(base + (size_t)grow * HSZ + q * 256, dst, (r & 7) << 4, q);
    }
    if (tid < 32) {
      const int grow = FH + ((tid >> 3) << 10) + j1 + (tid & 7);
      biasL[tid] = A.bih[grow] + A.bhh[grow];
    }
    const int uu = tid & 7, b = tid >> 3;      // ew cell (uu, b)
    float cst = A.c0[BSZ * HSZ + (size_t)b * HSZ + j1 + uu];
    __syncthreads();
    unsigned* myflag = A.bar + wg;
    const unsigned* rel = A.bar + 256 + (wg & 7) * 32;
    if (tid == 0) flagst(myflag, 1u);
    const int role = wv >> 1, kh = wv & 1;

    for (int t = 0; t < TSZ; ++t) {
      waitrel(rel, (unsigned)(t + 1), tid);
      const u16* x1 = A.H0 + (size_t)(t + 1) * (BSZ * HSZ);
      const u16* hp = (t == 0) ? A.h1init : A.H1 + (size_t)(t - 1) * HSZ;
      const size_t hstr = (t == 0) ? (size_t)HSZ : (size_t)TSZ * HSZ;
      const char* Wsel = role ? WhL : WxL;
      const u16 *s0, *s1;
      if (role == 0) {
        s0 = x1 + (size_t)l15 * HSZ + (kh << 9) + (lq << 3);
        s1 = s0 + 16 * HSZ;
      } else {
        s0 = hp + (size_t)l15 * hstr + (kh << 9) + (lq << 3);
        s1 = hp + (size_t)(l15 + 16) * hstr + (kh << 9) + (lq << 3);
      }
      short8 a0[16], a1[16];
      cohld16x16(s0, a0);
      cohld16x16(s1, a1);
      __builtin_amdgcn_sched_barrier(0);
      f32x4 acc[2][2];
      { f32x4 z = {0.f,0.f,0.f,0.f}; acc[0][0]=z; acc[0][1]=z; acc[1][0]=z; acc[1][1]=z; }
#pragma unroll
      for (int k = 0; k < 16; ++k) {
        const int kbyte = (((kh << 4) + k) << 6) + (lq << 4);
        short8 b0f = ldsB(Wsel, l15, kbyte);
        short8 b1f = ldsB(Wsel, 16 + l15, kbyte);
        acc[0][0] = mfma16(a0[k], b0f, acc[0][0]);
        acc[0][1] = mfma16(a1[k], b0f, acc[0][1]);
        acc[1][0] = mfma16(a0[k], b1f, acc[1][0]);
        acc[1][1] = mfma16(a1[k], b1f, acc[1][1]);
      }
#pragma unroll
      for (int tr = 0; tr < 2; ++tr)
#pragma unroll
        for (int hf = 0; hf < 2; ++hf)
          part_wr(part, wv, (tr << 4) + l15, (hf << 4) + (lq << 2), acc[tr][hf]);
      __syncthreads();
      const bool last = (t == TSZ - 1);
      {
        const int bs = b ^ (uu << 2);
        float gi = biasL[uu], gf = biasL[8 + uu], gg = biasL[16 + uu], go = biasL[24 + uu];
#pragma unroll
        for (int w2 = 0; w2 < 4; ++w2) {
          const float* pb = part + (w2 << 10);
          gi += pb[(uu << 5) + bs];
          gf += pb[((8 + uu) << 5) + bs];
          gg += pb[((16 + uu) << 5) + bs];
          go += pb[((24 + uu) << 5) + bs];
        }
        float i_ = sigm(gi), f_ = sigm(gf), g_ = tanh_fast(gg), o_ = sigm(go);
        float c_ = f_ * cst + i_ * g_;
        cst = c_;
        float h_ = o_ * tanh_fast(c_);
        cohst1_u16(A.H1 + (size_t)b * (TSZ * HSZ) + (size_t)t * HSZ + j1 + uu, f2bf(h_));
        if (last) {
          A.out_hc[BSZ * HSZ + (size_t)b * HSZ + j1 + uu] = h_;
          A.out_hc[3 * BSZ * HSZ + (size_t)b * HSZ + j1 + uu] = c_;
        }
      }
      __syncthreads();
      if (tid == 0) flagst(myflag, (unsigned)(t + 2));
    }
  } else {
    // ===== master poll block =====
    for (unsigned g = 1; g <= (unsigned)TSZ; ++g) {
      int done;
      do {
        unsigned v = 0xFFFFFFFFu;
        if (tid < NWRK) v = flagld(A.bar + tid);
        done = __syncthreads_and((int)(v >= g));
      } while (!done);
      if (tid < 8) flagst(A.bar + 256 + tid * 32, g);
    }
  }
}

// ---------- logsumexp finish ----------
__global__ void lse_kernel(float* __restrict__ rowsum, int n) {
  int i = blockIdx.x * 256 + threadIdx.x;
  if (i < n) rowsum[i] = logf(rowsum[i]);
}

__global__ __launch_bounds__(256) void lsm_finish(float* __restrict__ C,
                                                  const float* __restrict__ lse, int Vd) {
  int row = blockIdx.y;
  size_t start = (size_t)row * (size_t)Vd;
  int head = (int)((4 - (start & 3)) & 3);
  float s = lse[row];
  int i = blockIdx.x * 256 + threadIdx.x;
  if (blockIdx.x == 0 && i < head) C[start + i] -= s;
  int col = head + i * 4;
  if (col + 3 < Vd) {
    float4 v = *(float4*)(C + start + col);
    v.x -= s; v.y -= s; v.z -= s; v.w -= s;
    *(float4*)(C + start + col) = v;
  } else {
    for (int j = col; j < Vd; ++j) C[start + j] -= s;
  }
}

// ---------- launcher ----------
extern "C" void kernel_launch(void* const* d_in, const int* in_sizes, int n_in,
                              void* d_out, int out_size, void* d_ws, size_t ws_size,
                              hipStream_t stream) {
  const int* tokens = (const int*)d_in[0];
  const float* emb = (const float*)d_in[1];
  const float* Wih = (const float*)d_in[2];
  const float* Whh = (const float*)d_in[3];
  const float* bih = (const float*)d_in[4];
  const float* bhh = (const float*)d_in[5];
  const float* Wout = (const float*)d_in[6];
  const float* bout = (const float*)d_in[7];
  const float* h0 = (const float*)d_in[8];
  const float* c0 = (const float*)d_in[9];
  float* out = (float*)d_out;

  char* w = (char*)d_ws;
  size_t o = 0;
  u16* Xbf = (u16*)(w + o);    o += (size_t)M4 * HSZ * 2;
  u16* Wih0bf = (u16*)(w + o); o += (size_t)FH * HSZ * 2;
  u16* G0T = (u16*)(w + o);    o += (size_t)FH * M4 * 2;
  u16* H0 = (u16*)(w + o);     o += (size_t)(TSZ + 1) * BSZ * HSZ * 2;
  u16* H1 = (u16*)(w + o);     o += (size_t)BSZ * TSZ * HSZ * 2;
  u16* h1init = (u16*)(w + o); o += (size_t)BSZ * HSZ * 2;
  float* bias0 = (float*)(w + o);  o += FH * 4;
  float* rowsum = (float*)(w + o); o += M4 * 4;
  unsigned* bar = (unsigned*)(w + o); o += 4096;
  u16* Woutbf = (u16*)(w + o);
  size_t need_full = o + (size_t)VSZ * HSZ * 2;
  const bool bcvt = (ws_size < need_full);

  prep_misc<<<16, 256, 0, stream>>>(bih, bhh, bias0, rowsum, bar);
  prep_h<<<128, 256, 0, stream>>>(h0, H0, h1init);
  cvt_bf16<<<2048, 256, 0, stream>>>(Wih, Wih0bf, FH * HSZ / 4);
  if (!bcvt)
    cvt_bf16<<<4096, 256, 0, stream>>>(Wout, Woutbf, (int)((size_t)VSZ * HSZ / 4));
  embed_kernel<<<M4, 256, 0, stream>>>(tokens, emb, Xbf);
  // G0T[4H][M4] = Wih0 @ X^T + (b_ih0 + b_hh0)   (bias per row)
  gemm_bt<2, false><<<32 * 32, 256, 0, stream>>>(Wih0bf, Xbf, G0T, bias0, nullptr,
                                                 32, 32, M4, HSZ, M4);

  LstmArgs la{G0T, Wih, Whh, bih, bhh, c0, H0, H1, h1init,
              out + (size_t)OUT_LOGP, bar};
  void* kargs[] = {&la};
  hipFuncSetAttribute((const void*)lstm_coop, hipFuncAttributeMaxDynamicSharedMemorySize, LDSB);
  hipLaunchCooperativeKernel((const void*)lstm_coop, dim3(NBLK), dim3(256), kargs, LDSB, stream);

  const int nn = (VSZ + 127) / 128;  // 393
  if (!bcvt)
    gemm_bt<1, false><<<32 * nn, 256, 0, stream>>>(H1, Woutbf, out, bout, rowsum,
                                                   32, nn, VSZ, HSZ, VSZ);
  else
    gemm_bt<1, true><<<32 * nn, 256, 0, stream>>>(H1, Wout, out, bout, rowsum,
                                                  32, nn, VSZ, HSZ, VSZ);

  lse_kernel<<<16, 256, 0, stream>>>(rowsum, M4);
  lsm_finish<<<dim3(50, M4), 256, 0, stream>>>(out, rowsum, VSZ);
}

// Round 5
// 2233.450 us; speedup vs baseline: 2.4720x; 1.1093x over previous
//
#include <hip/hip_runtime.h>
#include <cstdint>
#include <cstddef>

#define DEVI __device__ __forceinline__

typedef __attribute__((ext_vector_type(8))) short short8;
typedef __attribute__((ext_vector_type(4))) float f32x4;
using u16 = unsigned short;

constexpr int BSZ = 32, TSZ = 128, VSZ = 50257, HSZ = 1024;
constexpr int M4 = BSZ * TSZ;          // 4096 rows
constexpr int FH = 4 * HSZ;            // 4096 gate rows
constexpr long long OUT_LOGP = (long long)M4 * VSZ;
constexpr int NWRK = 192;              // 64 layer0 + 128 layer1 worker blocks
constexpr int LDSB = 147584;           // dynamic LDS bytes

// ---------- small helpers ----------
DEVI u16 f2bf(float f) {
  unsigned u = __float_as_uint(f);
  unsigned r = (u + 0x7fffu + ((u >> 16) & 1u)) >> 16;
  return (u16)r;
}
DEVI float bf2f(u16 u) { return __uint_as_float(((unsigned)u) << 16); }
DEVI float sigm(float x) { return 1.f / (1.f + __expf(-x)); }
DEVI float tanh_fast(float x) { return 1.f - 2.f / (1.f + __expf(2.f * x)); }

DEVI f32x4 mfma16(short8 a, short8 b, f32x4 c) {
  return __builtin_amdgcn_mfma_f32_16x16x32_bf16(a, b, c, 0, 0, 0);
}

DEVI void gld16(const void* g, void* l) {
  auto gp = (const __attribute__((address_space(1))) unsigned int*)g;
  auto lp = (__attribute__((address_space(3))) unsigned int*)l;
  __builtin_amdgcn_global_load_lds(gp, lp, 16, 0, 0);
}

// ---------- SAFE coherent primitives (each asm block drains its own vmcnt) ----------
DEVI void cohld16x16(const u16* base, short8 (&d)[16]) {
  asm volatile(
      "global_load_dwordx4 %0, %16, off sc0 sc1\n\t"
      "global_load_dwordx4 %1, %16, off offset:64 sc0 sc1\n\t"
      "global_load_dwordx4 %2, %16, off offset:128 sc0 sc1\n\t"
      "global_load_dwordx4 %3, %16, off offset:192 sc0 sc1\n\t"
      "global_load_dwordx4 %4, %16, off offset:256 sc0 sc1\n\t"
      "global_load_dwordx4 %5, %16, off offset:320 sc0 sc1\n\t"
      "global_load_dwordx4 %6, %16, off offset:384 sc0 sc1\n\t"
      "global_load_dwordx4 %7, %16, off offset:448 sc0 sc1\n\t"
      "global_load_dwordx4 %8, %16, off offset:512 sc0 sc1\n\t"
      "global_load_dwordx4 %9, %16, off offset:576 sc0 sc1\n\t"
      "global_load_dwordx4 %10, %16, off offset:640 sc0 sc1\n\t"
      "global_load_dwordx4 %11, %16, off offset:704 sc0 sc1\n\t"
      "global_load_dwordx4 %12, %16, off offset:768 sc0 sc1\n\t"
      "global_load_dwordx4 %13, %16, off offset:832 sc0 sc1\n\t"
      "global_load_dwordx4 %14, %16, off offset:896 sc0 sc1\n\t"
      "global_load_dwordx4 %15, %16, off offset:960 sc0 sc1\n\t"
      "s_waitcnt vmcnt(0)"
      : "=&v"(d[0]), "=&v"(d[1]), "=&v"(d[2]), "=&v"(d[3]),
        "=&v"(d[4]), "=&v"(d[5]), "=&v"(d[6]), "=&v"(d[7]),
        "=&v"(d[8]), "=&v"(d[9]), "=&v"(d[10]), "=&v"(d[11]),
        "=&v"(d[12]), "=&v"(d[13]), "=&v"(d[14]), "=&v"(d[15])
      : "v"(base)
      : "memory");
}
DEVI void cohst2_u16(u16* p0, u16 v0, u16* p1, u16 v1) {
  asm volatile(
      "global_store_short %0, %2, off sc0 sc1\n\t"
      "global_store_short %1, %3, off sc0 sc1\n\t"
      "s_waitcnt vmcnt(0)"
      :: "v"(p0), "v"(p1), "v"((unsigned)v0), "v"((unsigned)v1)
      : "memory");
}
DEVI void cohst1_u16(u16* p0, u16 v0) {
  asm volatile(
      "global_store_short %0, %1, off sc0 sc1\n\t"
      "s_waitcnt vmcnt(0)"
      :: "v"(p0), "v"((unsigned)v0)
      : "memory");
}
DEVI void flagst(unsigned* p, unsigned v) {
  __hip_atomic_store(p, v, __ATOMIC_RELAXED, __HIP_MEMORY_SCOPE_AGENT);
}
DEVI unsigned flagld(const unsigned* p) {
  return __hip_atomic_load(p, __ATOMIC_RELAXED, __HIP_MEMORY_SCOPE_AGENT);
}

// wave-parallel flag waits: lane l polls flag l (no __syncthreads needed)
DEVI void wait64(const unsigned* f, unsigned g, int l) {
  while (!__all((int)(flagld(f + l) >= g))) __builtin_amdgcn_s_sleep(1);
}
DEVI void wait128(const unsigned* f, unsigned g, int l) {
  for (;;) {
    unsigned a = flagld(f + l);
    unsigned b = flagld(f + 64 + l);
    if (__all((int)((a >= g) && (b >= g)))) break;
    __builtin_amdgcn_s_sleep(1);
  }
}

// ---------- prep kernels ----------
__global__ void prep_misc(const float* __restrict__ bih, const float* __restrict__ bhh,
                          float* __restrict__ bias0, float* __restrict__ rowsum,
                          unsigned* __restrict__ bar) {
  int i = blockIdx.x * 256 + threadIdx.x;
  if (i < FH) { bias0[i] = bih[i] + bhh[i]; rowsum[i] = 0.f; }
  if (i < 1024) bar[i] = 0u;
}

__global__ void prep_h(const float* __restrict__ h0, u16* __restrict__ H0,
                       u16* __restrict__ h1init) {
  int i = blockIdx.x * 256 + threadIdx.x;   // 0..32767
  H0[i] = f2bf(h0[i]);
  h1init[i] = f2bf(h0[BSZ * HSZ + i]);
}

__global__ void cvt_bf16(const float* __restrict__ src, u16* __restrict__ dst, int n4) {
  int i = blockIdx.x * blockDim.x + threadIdx.x;
  int stride = gridDim.x * blockDim.x;
  for (; i < n4; i += stride) {
    float4 v = ((const float4*)src)[i];
    ushort4 o; o.x = f2bf(v.x); o.y = f2bf(v.y); o.z = f2bf(v.z); o.w = f2bf(v.w);
    ((ushort4*)dst)[i] = o;
  }
}

__global__ __launch_bounds__(256) void embed_kernel(const int* __restrict__ tok,
                                                    const float* __restrict__ emb,
                                                    u16* __restrict__ X) {
  int m = blockIdx.x;                // m = t*32 + b
  int t = m >> 5, b = m & 31;
  int token = tok[b * TSZ + t];
  const float4* src = (const float4*)(emb + (size_t)token * HSZ);
  int i = threadIdx.x;
  float4 v = src[i];
  ushort4 o; o.x = f2bf(v.x); o.y = f2bf(v.y); o.z = f2bf(v.z); o.w = f2bf(v.w);
  *(ushort4*)(X + (size_t)m * HSZ + i * 4) = o;
}

// ---------- 128x128 bf16 MFMA GEMM: C = A * B^T ----------
template <int EPI, bool BCVT>
__global__ __launch_bounds__(256) void gemm_bt(const u16* __restrict__ A,
                                               const void* __restrict__ Bsrc,
                                               void* __restrict__ Cout,
                                               const float* __restrict__ bias,
                                               float* __restrict__ rowsum,
                                               int nm, int nn, int N, int K, int ldc) {
  __shared__ u16 As[128 * 32];
  __shared__ u16 Bs[128 * 32];
  const int tid = threadIdx.x;
  int gsz = nm * nn;
  int id = blockIdx.x;
  int wg = ((gsz & 7) == 0) ? (id % 8) * (gsz >> 3) + (id >> 3) : id;
  const int bm = wg % nm, bn = wg / nm;
  const int m0 = bm * 128, n0 = bn * 128;
  const int l = tid & 63, wid = tid >> 6;
  const int wm = wid >> 1, wn = wid & 1;

  const int srow = tid >> 2, sq = tid & 3;
  const int arow0 = m0 + srow, arow1 = m0 + 64 + srow;
  int brow0 = n0 + srow;      if (brow0 > N - 1) brow0 = N - 1;
  int brow1 = n0 + 64 + srow; if (brow1 > N - 1) brow1 = N - 1;

  const u16* Bbf = (const u16*)Bsrc;
  const float* Bf32 = (const float*)Bsrc;
  u16* AsW = As + (size_t)(tid >> 6) * 512;
  u16* BsW = Bs + (size_t)(tid >> 6) * 512;

  f32x4 acc[4][4];
  f32x4 z = {0.f, 0.f, 0.f, 0.f};
#pragma unroll
  for (int a = 0; a < 4; ++a)
#pragma unroll
    for (int b = 0; b < 4; ++b) acc[a][b] = z;

  for (int k0 = 0; k0 < K; k0 += 32) {
    gld16(A + (size_t)arow0 * K + k0 + sq * 8, AsW);
    gld16(A + (size_t)arow1 * K + k0 + sq * 8, AsW + 2048);
    if (!BCVT) {
      gld16(Bbf + (size_t)brow0 * K + k0 + sq * 8, BsW);
      gld16(Bbf + (size_t)brow1 * K + k0 + sq * 8, BsW + 2048);
    } else {
      const float* s0 = Bf32 + (size_t)brow0 * K + k0 + sq * 8;
      const float* s1 = Bf32 + (size_t)brow1 * K + k0 + sq * 8;
      float4 x0 = *(const float4*)s0, y0 = *(const float4*)(s0 + 4);
      float4 x1 = *(const float4*)s1, y1 = *(const float4*)(s1 + 4);
      short8 v0, v1;
      v0[0]=(short)f2bf(x0.x); v0[1]=(short)f2bf(x0.y); v0[2]=(short)f2bf(x0.z); v0[3]=(short)f2bf(x0.w);
      v0[4]=(short)f2bf(y0.x); v0[5]=(short)f2bf(y0.y); v0[6]=(short)f2bf(y0.z); v0[7]=(short)f2bf(y0.w);
      v1[0]=(short)f2bf(x1.x); v1[1]=(short)f2bf(x1.y); v1[2]=(short)f2bf(x1.z); v1[3]=(short)f2bf(x1.w);
      v1[4]=(short)f2bf(y1.x); v1[5]=(short)f2bf(y1.y); v1[6]=(short)f2bf(y1.z); v1[7]=(short)f2bf(y1.w);
      *(short8*)&Bs[(size_t)tid * 8] = v0;
      *(short8*)&Bs[(size_t)tid * 8 + 2048] = v1;
    }
    __syncthreads();
    short8 af[4], bfr[4];
#pragma unroll
    for (int x = 0; x < 4; ++x) {
      int ar = wm * 64 + x * 16 + (l & 15);
      af[x] = *(const short8*)&As[ar * 32 + ((l >> 4) << 3)];
      int br = wn * 64 + x * 16 + (l & 15);
      bfr[x] = *(const short8*)&Bs[br * 32 + ((l >> 4) << 3)];
    }
#pragma unroll
    for (int mf = 0; mf < 4; ++mf)
#pragma unroll
      for (int nf = 0; nf < 4; ++nf)
        acc[mf][nf] = mfma16(af[mf], bfr[nf], acc[mf][nf]);
    __syncthreads();
  }

  if constexpr (EPI == 2) {
    u16* C = (u16*)Cout;
#pragma unroll
    for (int mf = 0; mf < 4; ++mf) {
      int rbase = m0 + wm * 64 + mf * 16 + ((l >> 4) << 2);
      float bvr[4];
#pragma unroll
      for (int j = 0; j < 4; ++j) bvr[j] = bias[rbase + j];
#pragma unroll
      for (int nf = 0; nf < 4; ++nf) {
        int cg = n0 + wn * 64 + nf * 16 + (l & 15);
#pragma unroll
        for (int j = 0; j < 4; ++j)
          C[(size_t)(rbase + j) * ldc + cg] = f2bf(acc[mf][nf][j] + bvr[j]);
      }
    }
  } else {
    float* C = (float*)Cout;
    int cg[4]; float bv[4]; bool ok[4];
#pragma unroll
    for (int nf = 0; nf < 4; ++nf) {
      cg[nf] = n0 + wn * 64 + nf * 16 + (l & 15);
      ok[nf] = (cg[nf] < N);
      bv[nf] = ok[nf] ? bias[cg[nf]] : 0.f;
    }
#pragma unroll
    for (int mf = 0; mf < 4; ++mf) {
#pragma unroll
      for (int j = 0; j < 4; ++j) {
        int r = m0 + wm * 64 + mf * 16 + ((l >> 4) << 2) + j;
        float e = 0.f;
#pragma unroll
        for (int nf = 0; nf < 4; ++nf) {
          float v = acc[mf][nf][j] + bv[nf];
          if (ok[nf]) { C[(size_t)r * ldc + cg[nf]] = v; e += __expf(v); }
        }
        e += __shfl_xor(e, 1, 16); e += __shfl_xor(e, 2, 16);
        e += __shfl_xor(e, 4, 16); e += __shfl_xor(e, 8, 16);
        if ((l & 15) == 0) atomicAdd(&rowsum[r], e);
      }
    }
  }
}

// ---------- cooperative 2-layer LSTM: direct flag polling, no master ----------
// bar: f0[wg] = bar[0..63] (L0 block wg flags t+1 after H0 slot t+1 stored)
//      f1[w]  = bar[64..191] (L1 block w flags t+1 after h1_t stored)
// L0 iter t: wait all f0 >= t (t>0). No L1 dependency (H0 slots write-once).
// L1 iter t: wait all f0 >= t+1 -> x phase; wait all f1 >= t -> h phase.
struct LstmArgs {
  const u16* G0T;      // [4H, M4] bf16: Wih0 @ X^T + (b_ih0+b_hh0), gate-major
  const float* Wih;    // [2,4H,H] f32
  const float* Whh;
  const float* bih, *bhh, *c0;
  u16* H0;             // [T+1, B, H]
  u16* H1;             // [B, T, H]
  const u16* h1init;   // [B, H]
  float* out_hc;       // hT[2][B][H] then cT[2][B][H]
  unsigned* bar;
};

// stage a 256-float quarter of a [1024] f32 row into a 2KB bf16 LDS row (XOR-swizzled)
DEVI void stage_row_q(const float* src, char* row, int sw, int q) {
  for (int kk = 0; kk < 256; kk += 8) {
    float4 x = *(const float4*)(src + kk);
    float4 y = *(const float4*)(src + kk + 4);
    short8 v;
    v[0]=(short)f2bf(x.x); v[1]=(short)f2bf(x.y); v[2]=(short)f2bf(x.z); v[3]=(short)f2bf(x.w);
    v[4]=(short)f2bf(y.x); v[5]=(short)f2bf(y.y); v[6]=(short)f2bf(y.z); v[7]=(short)f2bf(y.w);
    const int kbyte = (q * 256 + kk) * 2;
    *(short8*)(row + (kbyte ^ sw)) = v;
  }
}

DEVI short8 ldsB(const char* lds, int r, int kbyte) {
  return *(const short8*)(lds + (size_t)r * 2048 + (kbyte ^ ((r & 7) << 4)));
}

// part layout: [wave][R rows][16 cols], f32x4 slot-XOR: slot = lq ^ (R&3)
DEVI void part_wr(float* part, int wstride_log2, int wv, int R, int lq, f32x4 v) {
  *(f32x4*)&part[(wv << wstride_log2) + (R << 4) + ((lq ^ (R & 3)) << 2)] = v;
}
DEVI float part_rd(const float* part, int wstride_log2, int wv, int R, int c) {
  return part[(wv << wstride_log2) + (R << 4) + ((((c >> 2) ^ (R & 3)) << 2)) + (c & 3)];
}

__global__ __launch_bounds__(256, 1) void lstm_coop(LstmArgs A) {
  extern __shared__ char smem[];
  const int wg = blockIdx.x, tid = threadIdx.x;
  const int wv = tid >> 6, l = tid & 63;
  const int l15 = l & 15, lq = l >> 4;
  const int bh = wv >> 1, kh = wv & 1;   // batch-half, K-half

  if (wg < 64) {
    // ===== layer 0: 16 units/block; wave = (batch-half bh) x (K-half kh) =====
    char* WL = smem;                        // Whh0 rows [64 = gate*16+u][2048B]
    float* part = (float*)(smem + 131072);  // [4][64][16] f32
    const int j0 = wg << 4;
    {
      const int R = tid >> 2, q = tid & 3;          // R = gate*16 + u
      const int grow = ((R >> 4) << 10) + j0 + (R & 15);
      stage_row_q(A.Whh + (size_t)grow * HSZ + q * 256, WL + (size_t)R * 2048,
                  (R & 7) << 4, q);
    }
    const int uu = tid & 15, bb = tid >> 4;          // ew cells (uu,bb),(uu,bb+16)
    float cst[2];
    cst[0] = A.c0[(size_t)bb * HSZ + j0 + uu];
    cst[1] = A.c0[(size_t)(bb + 16) * HSZ + j0 + uu];
    __syncthreads();
    unsigned* myflag = A.bar + wg;

    for (int t = 0; t < TSZ; ++t) {
      // prefetch this tick's G0T contributions (static; completes under the wait)
      float g0v[4][2];
      {
        const int col = t * 32;
#pragma unroll
        for (int g4 = 0; g4 < 4; ++g4) {
          const u16* gp = A.G0T + (size_t)((g4 << 10) + j0 + uu) * M4 + col;
          g0v[g4][0] = bf2f(gp[bb]);
          g0v[g4][1] = bf2f(gp[bb + 16]);
        }
      }
      if (t > 0) wait64(A.bar, (unsigned)t, l);
      const u16* hprev = A.H0 + (size_t)t * (BSZ * HSZ);
      const u16* hb = hprev + (size_t)(bh * 16 + l15) * HSZ + (kh << 9) + (lq << 3);
      short8 a[16];
      cohld16x16(hb, a);
      __builtin_amdgcn_sched_barrier(0);
      f32x4 acc[4];
      { f32x4 z = {0.f,0.f,0.f,0.f}; acc[0]=z; acc[1]=z; acc[2]=z; acc[3]=z; }
#pragma unroll
      for (int k = 0; k < 16; ++k) {
        const int kbyte = (((kh << 4) + k) << 6) + (lq << 4);
#pragma unroll
        for (int tr = 0; tr < 4; ++tr)
          acc[tr] = mfma16(a[k], ldsB(WL, (tr << 4) + l15, kbyte), acc[tr]);
      }
#pragma unroll
      for (int tr = 0; tr < 4; ++tr)
        part_wr(part, 10, wv, (tr << 4) + l15, lq, acc[tr]);
      __syncthreads();
      const bool last = (t == TSZ - 1);
      u16* hnext = A.H0 + (size_t)(t + 1) * (BSZ * HSZ);
      u16 hv[2];
#pragma unroll
      for (int pp = 0; pp < 2; ++pp) {
        const int b = bb + (pp << 4);
        float gi = g0v[0][pp], gf = g0v[1][pp], gg = g0v[2][pp], go = g0v[3][pp];
#pragma unroll
        for (int kh2 = 0; kh2 < 2; ++kh2) {
          const int w2 = (pp << 1) | kh2;
          gi += part_rd(part, 10, w2, uu, bb);
          gf += part_rd(part, 10, w2, 16 + uu, bb);
          gg += part_rd(part, 10, w2, 32 + uu, bb);
          go += part_rd(part, 10, w2, 48 + uu, bb);
        }
        float i_ = sigm(gi), f_ = sigm(gf), g_ = tanh_fast(gg), o_ = sigm(go);
        float c_ = f_ * cst[pp] + i_ * g_;
        cst[pp] = c_;
        float h_ = o_ * tanh_fast(c_);
        hv[pp] = f2bf(h_);
        if (last) {
          A.out_hc[(size_t)b * HSZ + j0 + uu] = h_;
          A.out_hc[2 * BSZ * HSZ + (size_t)b * HSZ + j0 + uu] = c_;
        }
      }
      cohst2_u16(hnext + (size_t)bb * HSZ + j0 + uu, hv[0],
                 hnext + (size_t)(bb + 16) * HSZ + j0 + uu, hv[1]);
      __syncthreads();
      if (tid == 0) flagst(myflag, (unsigned)(t + 1));
    }
  } else {
    // ===== layer 1: 8 units/block; wave = (batch-half bh) x (K-half kh) =====
    char* WxL = smem;                         // Wih1 rows [32 = gate*8+u][2048B]
    char* WhL = smem + 65536;                 // Whh1 rows [32][2048B]
    float* part = (float*)(smem + 131072);    // [4][32][16] f32
    float* biasL = (float*)(smem + 139264);   // [32]
    const int lw = wg - 64;
    const int j1 = lw << 3;
    {
      const int rr = tid >> 2, q = tid & 3;
      const int r = rr & 31;                   // r = gate*8 + u
      const int grow = FH + ((r >> 3) << 10) + j1 + (r & 7);
      const float* base = (rr >= 32) ? A.Whh : A.Wih;
      char* dst = ((rr >= 32) ? WhL : WxL) + (size_t)r * 2048;
      stage_row_q(base + (size_t)grow * HSZ + q * 256, dst, (r & 7) << 4, q);
    }
    if (tid < 32) {
      const int grow = FH + ((tid >> 3) << 10) + j1 + (tid & 7);
      biasL[tid] = A.bih[grow] + A.bhh[grow];
    }
    const int uu = tid & 7, b1 = tid >> 3;     // ew cell (uu, b1)
    float cst = A.c0[BSZ * HSZ + (size_t)b1 * HSZ + j1 + uu];
    __syncthreads();
    unsigned* myflag = A.bar + 64 + lw;

    for (int t = 0; t < TSZ; ++t) {
      // ---- x phase: needs H0 slot t+1 (L0 runs ahead; wait usually instant)
      wait64(A.bar, (unsigned)(t + 1), l);
      const u16* x1 = A.H0 + (size_t)(t + 1) * (BSZ * HSZ);
      const u16* xb = x1 + (size_t)(bh * 16 + l15) * HSZ + (kh << 9) + (lq << 3);
      short8 ax[16];
      cohld16x16(xb, ax);
      __builtin_amdgcn_sched_barrier(0);
      f32x4 acc[2];
      { f32x4 z = {0.f,0.f,0.f,0.f}; acc[0]=z; acc[1]=z; }
#pragma unroll
      for (int k = 0; k < 16; ++k) {
        const int kbyte = (((kh << 4) + k) << 6) + (lq << 4);
        acc[0] = mfma16(ax[k], ldsB(WxL, l15, kbyte), acc[0]);
        acc[1] = mfma16(ax[k], ldsB(WxL, 16 + l15, kbyte), acc[1]);
      }
      // ---- h phase: needs own-layer h1[t-1]
      if (t > 0) wait128(A.bar + 64, (unsigned)t, l);
      const u16* hp = (t == 0) ? A.h1init : A.H1 + (size_t)(t - 1) * HSZ;
      const size_t hstr = (t == 0) ? (size_t)HSZ : (size_t)TSZ * HSZ;
      const u16* hbp = hp + (size_t)(bh * 16 + l15) * hstr + (kh << 9) + (lq << 3);
      short8 ah[16];
      cohld16x16(hbp, ah);
      __builtin_amdgcn_sched_barrier(0);
#pragma unroll
      for (int k = 0; k < 16; ++k) {
        const int kbyte = (((kh << 4) + k) << 6) + (lq << 4);
        acc[0] = mfma16(ah[k], ldsB(WhL, l15, kbyte), acc[0]);
        acc[1] = mfma16(ah[k], ldsB(WhL, 16 + l15, kbyte), acc[1]);
      }
#pragma unroll
      for (int tr = 0; tr < 2; ++tr)
        part_wr(part, 9, wv, (tr << 4) + l15, lq, acc[tr]);
      __syncthreads();
      const bool last = (t == TSZ - 1);
      {
        const int c = b1 & 15, ph = b1 >> 4;
        float gi = biasL[uu], gf = biasL[8 + uu], gg = biasL[16 + uu], go = biasL[24 + uu];
#pragma unroll
        for (int kh2 = 0; kh2 < 2; ++kh2) {
          const int w2 = (ph << 1) | kh2;
          gi += part_rd(part, 9, w2, uu, c);
          gf += part_rd(part, 9, w2, 8 + uu, c);
          gg += part_rd(part, 9, w2, 16 + uu, c);
          go += part_rd(part, 9, w2, 24 + uu, c);
        }
        float i_ = sigm(gi), f_ = sigm(gf), g_ = tanh_fast(gg), o_ = sigm(go);
        float c_ = f_ * cst + i_ * g_;
        cst = c_;
        float h_ = o_ * tanh_fast(c_);
        cohst1_u16(A.H1 + (size_t)b1 * (TSZ * HSZ) + (size_t)t * HSZ + j1 + uu, f2bf(h_));
        if (last) {
          A.out_hc[BSZ * HSZ + (size_t)b1 * HSZ + j1 + uu] = h_;
          A.out_hc[3 * BSZ * HSZ + (size_t)b1 * HSZ + j1 + uu] = c_;
        }
      }
      __syncthreads();
      if (tid == 0) flagst(myflag, (unsigned)(t + 1));
    }
  }
}

// ---------- logsumexp finish ----------
__global__ void lse_kernel(float* __restrict__ rowsum, int n) {
  int i = blockIdx.x * 256 + threadIdx.x;
  if (i < n) rowsum[i] = logf(rowsum[i]);
}

__global__ __launch_bounds__(256) void lsm_finish(float* __restrict__ C,
                                                  const float* __restrict__ lse, int Vd) {
  int row = blockIdx.y;
  size_t start = (size_t)row * (size_t)Vd;
  int head = (int)((4 - (start & 3)) & 3);
  float s = lse[row];
  int i = blockIdx.x * 256 + threadIdx.x;
  if (blockIdx.x == 0 && i < head) C[start + i] -= s;
  int col = head + i * 4;
  if (col + 3 < Vd) {
    float4 v = *(float4*)(C + start + col);
    v.x -= s; v.y -= s; v.z -= s; v.w -= s;
    *(float4*)(C + start + col) = v;
  } else {
    for (int j = col; j < Vd; ++j) C[start + j] -= s;
  }
}

// ---------- launcher ----------
extern "C" void kernel_launch(void* const* d_in, const int* in_sizes, int n_in,
                              void* d_out, int out_size, void* d_ws, size_t ws_size,
                              hipStream_t stream) {
  const int* tokens = (const int*)d_in[0];
  const float* emb = (const float*)d_in[1];
  const float* Wih = (const float*)d_in[2];
  const float* Whh = (const float*)d_in[3];
  const float* bih = (const float*)d_in[4];
  const float* bhh = (const float*)d_in[5];
  const float* Wout = (const float*)d_in[6];
  const float* bout = (const float*)d_in[7];
  const float* h0 = (const float*)d_in[8];
  const float* c0 = (const float*)d_in[9];
  float* out = (float*)d_out;

  char* w = (char*)d_ws;
  size_t o = 0;
  u16* Xbf = (u16*)(w + o);    o += (size_t)M4 * HSZ * 2;
  u16* Wih0bf = (u16*)(w + o); o += (size_t)FH * HSZ * 2;
  u16* G0T = (u16*)(w + o);    o += (size_t)FH * M4 * 2;
  u16* H0 = (u16*)(w + o);     o += (size_t)(TSZ + 1) * BSZ * HSZ * 2;
  u16* H1 = (u16*)(w + o);     o += (size_t)BSZ * TSZ * HSZ * 2;
  u16* h1init = (u16*)(w + o); o += (size_t)BSZ * HSZ * 2;
  float* bias0 = (float*)(w + o);  o += FH * 4;
  float* rowsum = (float*)(w + o); o += M4 * 4;
  unsigned* bar = (unsigned*)(w + o); o += 4096;
  u16* Woutbf = (u16*)(w + o);
  size_t need_full = o + (size_t)VSZ * HSZ * 2;
  const bool bcvt = (ws_size < need_full);

  prep_misc<<<16, 256, 0, stream>>>(bih, bhh, bias0, rowsum, bar);
  prep_h<<<128, 256, 0, stream>>>(h0, H0, h1init);
  cvt_bf16<<<2048, 256, 0, stream>>>(Wih, Wih0bf, FH * HSZ / 4);
  if (!bcvt)
    cvt_bf16<<<4096, 256, 0, stream>>>(Wout, Woutbf, (int)((size_t)VSZ * HSZ / 4));
  embed_kernel<<<M4, 256, 0, stream>>>(tokens, emb, Xbf);
  // G0T[4H][M4] = Wih0 @ X^T + (b_ih0 + b_hh0)   (bias per row)
  gemm_bt<2, false><<<32 * 32, 256, 0, stream>>>(Wih0bf, Xbf, G0T, bias0, nullptr,
                                                 32, 32, M4, HSZ, M4);

  LstmArgs la{G0T, Wih, Whh, bih, bhh, c0, H0, H1, h1init,
              out + (size_t)OUT_LOGP, bar};
  void* kargs[] = {&la};
  hipFuncSetAttribute((const void*)lstm_coop, hipFuncAttributeMaxDynamicSharedMemorySize, LDSB);
  hipLaunchCooperativeKernel((const void*)lstm_coop, dim3(NWRK), dim3(256), kargs, LDSB, stream);

  const int nn = (VSZ + 127) / 128;  // 393
  if (!bcvt)
    gemm_bt<1, false><<<32 * nn, 256, 0, stream>>>(H1, Woutbf, out, bout, rowsum,
                                                   32, nn, VSZ, HSZ, VSZ);
  else
    gemm_bt<1, true><<<32 * nn, 256, 0, stream>>>(H1, Wout, out, bout, rowsum,
                                                  32, nn, VSZ, HSZ, VSZ);

  lse_kernel<<<16, 256, 0, stream>>>(rowsum, M4);
  lsm_finish<<<dim3(50, M4), 256, 0, stream>>>(out, rowsum, VSZ);
}